// Round 12
// baseline (2847.112 us; speedup 1.0000x reference)
//
#include <hip/hip_runtime.h>
#include <hip/hip_bf16.h>
#include <math.h>

// Problem constants
#define V_SZ 32000
#define D_SZ 768
#define H_SZ 12
#define L_SZ 12
#define DF_SZ 3072
#define B_SZ 2
#define S_SZ 1024
#define BS_SZ 16
#define HD_SZ 64
#define MASK_ID 31999
#define NTOK (B_SZ * S_SZ)   // 2048

typedef __attribute__((ext_vector_type(8))) short bf16x8;
typedef __attribute__((ext_vector_type(4))) short bf16x4;
typedef __attribute__((ext_vector_type(4))) float f32x4;

union B8 { bf16x8 v; __hip_bfloat162 h[4]; };
union B4 { bf16x4 v; __hip_bfloat162 h[2]; };
union U4E { ushort4 u; unsigned short e[4]; };

__device__ inline unsigned short f2bf(float x) {
    __hip_bfloat16 b = __float2bfloat16(x);
    union { __hip_bfloat16 b; unsigned short u; } c; c.b = b;
    return c.u;
}

// Plain f32 -> bf16 cast, 8 elems/thread
__global__ __launch_bounds__(256) void conv_cast_kernel(
    const float* __restrict__ src, unsigned short* __restrict__ dst, int n8)
{
    int i = blockIdx.x * 256 + threadIdx.x;
    if (i >= n8) return;
    const float* p = src + (size_t)i * 8;
    float4 v0 = *(const float4*)p;
    float4 v1 = *(const float4*)(p + 4);
    B8 r;
    r.h[0] = __float22bfloat162_rn(float2{v0.x, v0.y});
    r.h[1] = __float22bfloat162_rn(float2{v0.z, v0.w});
    r.h[2] = __float22bfloat162_rn(float2{v1.x, v1.y});
    r.h[3] = __float22bfloat162_rn(float2{v1.z, v1.w});
    *(bf16x8*)(dst + (size_t)i * 8) = r.v;
}

// ---------------------------------------------------------------------------
// Embedding gather + rotary
// ---------------------------------------------------------------------------
__global__ __launch_bounds__(256) void embed_rot_kernel(
    const int* __restrict__ ids, const float* __restrict__ emb,
    float* __restrict__ x)
{
    const int tok = blockIdx.x;
    const int s = tok & (S_SZ - 1);
    const int id = ids[tok];
    const float* e = emb + (size_t)id * D_SZ;
    float* xo = x + (size_t)tok * D_SZ;
    const int t = threadIdx.x;

    if (t < 192) {
        float x0 = e[2 * t], x1 = e[2 * t + 1];
        float freq = powf(10000.f, -((float)(2 * t)) / 384.f);
        float ang = (float)s * freq;
        float sn, cs;
        sincosf(ang, &sn, &cs);
        xo[2 * t]     = x0 * cs - x1 * sn;
        xo[2 * t + 1] = x0 * sn + x1 * cs;
    }
    for (int ch = 384 + t; ch < D_SZ; ch += 256) xo[ch] = e[ch];
}

// ---------------------------------------------------------------------------
// MFMA bf16 GEMM, single-step prefetch (R10-best structure).
// LDS layout: linear 16B slots, slot c holds (row=c>>2, ksg=((c&3)+(c>>3))&3)
// -- K-subchunk swizzled within each row: coalesced global reads,
// conflict-free LDS writes AND reads (dsw = ((kgrp-(rc>>1))&3)*8).
//  AM: 0 f32 A; 1 f32 A + FULL fused LN (stats + lnw/lnb applied in staging,
//      BM==64); 2 bf16 A
//  CM: 0 f32 C (+Res); 1 qkv split epilogue; 2 GELU -> bf16 C;
//      3 raw f32 partial (split-K, no bias/res)
//  WB16: W bf16 (else f32, cvt in staging).  XSWZ: XCD swizzle.
//  CEP: per-block CE partials.  SPLITK: K-chunks along blockIdx.z.
// ---------------------------------------------------------------------------
template<int BM, int BN, int AM, int CM, bool WB16, bool XSWZ, bool CEP, int SPLITK>
__global__ __launch_bounds__(256) void mfma_gemm(
    const void* __restrict__ Av, const void* __restrict__ Wv,
    const float* __restrict__ bias, const float* __restrict__ Res,
    float* __restrict__ C,
    unsigned short* __restrict__ qp, unsigned short* __restrict__ kp,
    unsigned short* __restrict__ vp, float2* __restrict__ pm,
    const float* __restrict__ lnw, const float* __restrict__ lnb,
    int M, int N, int K)
{
    constexpr int MR = BM / 32;
    constexpr int NR = BN / 32;
    constexpr int ACH = BM * 4 / 256;         // 16B slots per thread (A)
    constexpr int BCH = BN * 4 / 256;

    __shared__ __align__(16) unsigned short As[2][BM * 32];
    __shared__ __align__(16) unsigned short Bs[2][BN * 32];
    __shared__ float smean[AM == 1 ? BM : 1];
    __shared__ float srstd[AM == 1 ? BM : 1];

    const int tid = threadIdx.x;
    const int lane = tid & 63;
    const int wave = tid >> 6;
    const int wrow0 = (wave >> 1) * (BM / 2);
    const int wcol0 = (wave & 1) * (BN / 2);
    const int kgrp = lane >> 4;
    const int rc = lane & 15;
    const int dsw = ((kgrp - (rc >> 1)) & 3) * 8;

    int m0, n0;
    if constexpr (XSWZ) {
        int id = blockIdx.y * gridDim.x + blockIdx.x;
        int cpx = (gridDim.x * gridDim.y) >> 3;
        int swz = (id & 7) * cpx + (id >> 3);
        m0 = (swz % gridDim.x) * BM;
        n0 = (swz / gridDim.x) * BN;
    } else {
        m0 = blockIdx.x * BM;
        n0 = blockIdx.y * BN;
    }
    const int kdiv = K / SPLITK;
    const int kbase = (SPLITK > 1) ? blockIdx.z * kdiv : 0;

    if constexpr (AM == 1) {
        const float* A = (const float*)Av;
        const int row = tid >> 2, q = tid & 3;
        const float* xr = A + (size_t)(m0 + row) * K + q * (K >> 2);
        float sum = 0.f, ss = 0.f;
        for (int j = 0; j < (K >> 4); ++j) {
            float4 v = *(const float4*)(xr + j * 4);
            sum += v.x + v.y + v.z + v.w;
            ss += v.x * v.x + v.y * v.y + v.z * v.z + v.w * v.w;
        }
        sum += __shfl_xor(sum, 1); sum += __shfl_xor(sum, 2);
        ss  += __shfl_xor(ss, 1);  ss  += __shfl_xor(ss, 2);
        float mean = sum * (1.f / (float)K);
        float var = ss * (1.f / (float)K) - mean * mean;
        if (q == 0) { smean[row] = mean; srstd[row] = rsqrtf(var + 1e-5f); }
        __syncthreads();
    }

    f32x4 acc[MR][NR];
#pragma unroll
    for (int i = 0; i < MR; ++i)
#pragma unroll
        for (int j = 0; j < NR; ++j) acc[i][j] = (f32x4){0.f, 0.f, 0.f, 0.f};

    float areg[(AM != 2) ? ACH : 1][8];
    bf16x8 areg16[(AM == 2) ? ACH : 1];
    float bregf[WB16 ? 1 : BCH][8];
    bf16x8 breg16[WB16 ? BCH : 1];

    // ---- A staging: slot c = tid + i*256; row = c>>2, ksg swizzled ----
    auto load_a = [&](int k0) {
#pragma unroll
        for (int i = 0; i < ACH; ++i) {
            int c = tid + i * 256;
            int row = c >> 2, ksg = ((c & 3) + (c >> 3)) & 3;
            if constexpr (AM == 2) {
                const unsigned short* A16 = (const unsigned short*)Av;
                areg16[i] = *(const bf16x8*)(A16 + (size_t)(m0 + row) * K + k0 + ksg * 8);
            } else {
                const float* p = (const float*)Av + (size_t)(m0 + row) * K + k0 + ksg * 8;
                float4 v0 = *(const float4*)p;
                float4 v1 = *(const float4*)(p + 4);
                areg[i][0] = v0.x; areg[i][1] = v0.y; areg[i][2] = v0.z; areg[i][3] = v0.w;
                areg[i][4] = v1.x; areg[i][5] = v1.y; areg[i][6] = v1.z; areg[i][7] = v1.w;
            }
        }
    };
    auto write_a = [&](int buf, int k0) {
#pragma unroll
        for (int i = 0; i < ACH; ++i) {
            int c = tid + i * 256;
            if constexpr (AM == 2) {
                *(bf16x8*)&As[buf][c * 8] = areg16[i];
            } else if constexpr (AM == 1) {
                int row = c >> 2, ksg = ((c & 3) + (c >> 3)) & 3;
                float sc = srstd[row], sh = -smean[row] * sc;
                const float* lw = lnw + k0 + ksg * 8;
                const float* lb = lnb + k0 + ksg * 8;
                float4 w0 = *(const float4*)lw;
                float4 w1 = *(const float4*)(lw + 4);
                float4 b0 = *(const float4*)lb;
                float4 b1 = *(const float4*)(lb + 4);
                B8 r;
                r.h[0] = __float22bfloat162_rn(float2{
                    fmaf(fmaf(areg[i][0], sc, sh), w0.x, b0.x),
                    fmaf(fmaf(areg[i][1], sc, sh), w0.y, b0.y)});
                r.h[1] = __float22bfloat162_rn(float2{
                    fmaf(fmaf(areg[i][2], sc, sh), w0.z, b0.z),
                    fmaf(fmaf(areg[i][3], sc, sh), w0.w, b0.w)});
                r.h[2] = __float22bfloat162_rn(float2{
                    fmaf(fmaf(areg[i][4], sc, sh), w1.x, b1.x),
                    fmaf(fmaf(areg[i][5], sc, sh), w1.y, b1.y)});
                r.h[3] = __float22bfloat162_rn(float2{
                    fmaf(fmaf(areg[i][6], sc, sh), w1.z, b1.z),
                    fmaf(fmaf(areg[i][7], sc, sh), w1.w, b1.w)});
                *(bf16x8*)&As[buf][c * 8] = r.v;
            } else {
                B8 r;
                r.h[0] = __float22bfloat162_rn(float2{areg[i][0], areg[i][1]});
                r.h[1] = __float22bfloat162_rn(float2{areg[i][2], areg[i][3]});
                r.h[2] = __float22bfloat162_rn(float2{areg[i][4], areg[i][5]});
                r.h[3] = __float22bfloat162_rn(float2{areg[i][6], areg[i][7]});
                *(bf16x8*)&As[buf][c * 8] = r.v;
            }
        }
    };

    // ---- B staging ----
    auto load_b = [&](int k0) {
#pragma unroll
        for (int i = 0; i < BCH; ++i) {
            int c = tid + i * 256;
            int row = c >> 2, ksg = ((c & 3) + (c >> 3)) & 3;
            if constexpr (WB16) {
                const unsigned short* W16 = (const unsigned short*)Wv;
                breg16[i] = *(const bf16x8*)(W16 + (size_t)(n0 + row) * K + k0 + ksg * 8);
            } else {
                const float* p = (const float*)Wv + (size_t)(n0 + row) * K + k0 + ksg * 8;
                float4 v0 = *(const float4*)p;
                float4 v1 = *(const float4*)(p + 4);
                bregf[i][0] = v0.x; bregf[i][1] = v0.y; bregf[i][2] = v0.z; bregf[i][3] = v0.w;
                bregf[i][4] = v1.x; bregf[i][5] = v1.y; bregf[i][6] = v1.z; bregf[i][7] = v1.w;
            }
        }
    };
    auto write_b = [&](int buf) {
#pragma unroll
        for (int i = 0; i < BCH; ++i) {
            int c = tid + i * 256;
            if constexpr (WB16) {
                *(bf16x8*)&Bs[buf][c * 8] = breg16[i];
            } else {
                B8 r;
                r.h[0] = __float22bfloat162_rn(float2{bregf[i][0], bregf[i][1]});
                r.h[1] = __float22bfloat162_rn(float2{bregf[i][2], bregf[i][3]});
                r.h[2] = __float22bfloat162_rn(float2{bregf[i][4], bregf[i][5]});
                r.h[3] = __float22bfloat162_rn(float2{bregf[i][6], bregf[i][7]});
                *(bf16x8*)&Bs[buf][c * 8] = r.v;
            }
        }
    };

    auto compute = [&](int buf) {
        bf16x8 af[MR], bf[NR];
#pragma unroll
        for (int mi = 0; mi < MR; ++mi)
            af[mi] = *(const bf16x8*)&As[buf][(wrow0 + mi * 16 + rc) * 32 + dsw];
#pragma unroll
        for (int ni = 0; ni < NR; ++ni)
            bf[ni] = *(const bf16x8*)&Bs[buf][(wcol0 + ni * 16 + rc) * 32 + dsw];
#pragma unroll
        for (int mi = 0; mi < MR; ++mi)
#pragma unroll
            for (int ni = 0; ni < NR; ++ni)
                acc[mi][ni] = __builtin_amdgcn_mfma_f32_16x16x32_bf16(
                    af[mi], bf[ni], acc[mi][ni], 0, 0, 0);
    };

    // ---- prologue ----
    load_a(kbase);
    load_b(kbase);
    write_a(0, kbase);
    write_b(0);
    __syncthreads();

    const int nk = kdiv >> 5;
    int cur = 0;
    for (int s = 0; s < nk; ++s) {
        const bool more = (s + 1 < nk);
        const int k1 = kbase + ((s + 1) << 5);
        if (more) { load_a(k1); load_b(k1); }
        compute(cur);
        if (more) { write_a(cur ^ 1, k1); write_b(cur ^ 1); }
        __syncthreads();
        cur ^= 1;
    }

    // ---- epilogue ----
#pragma unroll
    for (int mi = 0; mi < MR; ++mi) {
#pragma unroll
        for (int ni = 0; ni < NR; ++ni) {
            const int col = n0 + wcol0 + ni * 16 + rc;
            const int rbase = m0 + wrow0 + mi * 16 + kgrp * 4;
            if constexpr (CM == 1) {
                float bv = bias[col];
                const int region = col / 768;
                const int c768 = col - region * 768;
                const int hh = c768 >> 6, d = c768 & 63;
                const int bb = rbase >> 10, s0 = rbase & 1023;
                const int bh = bb * H_SZ + hh;
                if (region == 0) {
#pragma unroll
                    for (int i = 0; i < 4; ++i)
                        qp[((size_t)(bh << 10) + s0 + i) * 64 + d]
                            = f2bf((acc[mi][ni][i] + bv) * 0.125f);
                } else if (region == 1) {
#pragma unroll
                    for (int i = 0; i < 4; ++i)
                        kp[((size_t)(bh << 10) + s0 + i) * 64 + d]
                            = f2bf(acc[mi][ni][i] + bv);
                } else {
                    U4E t4;
#pragma unroll
                    for (int i = 0; i < 4; ++i) t4.e[i] = f2bf(acc[mi][ni][i] + bv);
                    *(ushort4*)&vp[(((size_t)bh * 64 + d) << 10) + s0] = t4.u;
                }
            } else if constexpr (CM == 2) {
                float bv = bias[col];
                unsigned short* C16 = (unsigned short*)C;
#pragma unroll
                for (int i = 0; i < 4; ++i) {
                    float v = acc[mi][ni][i] + bv;
                    v = 0.5f * v * (1.f + erff(v * 0.70710678118654752f));
                    C16[(size_t)(rbase + i) * N + col] = f2bf(v);
                }
            } else if constexpr (CM == 3) {
                float* P = C + (size_t)blockIdx.z * ((size_t)M * N);
                size_t basei = (size_t)rbase * N + col;
#pragma unroll
                for (int i = 0; i < 4; ++i)
                    P[basei + (size_t)i * N] = acc[mi][ni][i];
            } else {
                float bv = bias ? bias[col] : 0.f;
                size_t basei = (size_t)rbase * N + col;
#pragma unroll
                for (int i = 0; i < 4; ++i) {
                    float v = acc[mi][ni][i] + bv;
                    size_t idx = basei + (size_t)i * N;
                    if (Res) v += Res[idx];
                    C[idx] = v;
                }
            }
        }
    }

    // ---- fused CE partials (per-block row max & sumexp over BN cols) ----
    if constexpr (CEP) {
        float2 (*sce)[2] = (float2 (*)[2])As;    // reuse LDS (post-barrier)
        float bvv[NR];
#pragma unroll
        for (int ni = 0; ni < NR; ++ni) bvv[ni] = bias[n0 + wcol0 + ni * 16 + rc];
#pragma unroll
        for (int mi = 0; mi < MR; ++mi) {
#pragma unroll
            for (int i = 0; i < 4; ++i) {
                float vmax = -1e30f;
#pragma unroll
                for (int ni = 0; ni < NR; ++ni)
                    vmax = fmaxf(vmax, acc[mi][ni][i] + bvv[ni]);
                vmax = fmaxf(vmax, __shfl_xor(vmax, 1));
                vmax = fmaxf(vmax, __shfl_xor(vmax, 2));
                vmax = fmaxf(vmax, __shfl_xor(vmax, 4));
                vmax = fmaxf(vmax, __shfl_xor(vmax, 8));
                float ssum = 0.f;
#pragma unroll
                for (int ni = 0; ni < NR; ++ni)
                    ssum += __expf(acc[mi][ni][i] + bvv[ni] - vmax);
                ssum += __shfl_xor(ssum, 1);
                ssum += __shfl_xor(ssum, 2);
                ssum += __shfl_xor(ssum, 4);
                ssum += __shfl_xor(ssum, 8);
                if (rc == 0)
                    sce[wrow0 + mi * 16 + kgrp * 4 + i][wave & 1] = float2{vmax, ssum};
            }
        }
        __syncthreads();
        if (tid < BM) {
            float2 a = sce[tid][0], b2 = sce[tid][1];
            float Mv = fmaxf(a.x, b2.x);
            float Sv = a.y * __expf(a.x - Mv) + b2.y * __expf(b2.x - Mv);
            pm[(size_t)(n0 >> 7) * NTOK + m0 + tid] = float2{Mv, Sv};
        }
    }
}

// ---------------------------------------------------------------------------
// ffn2 split-K reduce: x += b2 + sum_z pp[z]   (8 f32 per thread)
// ---------------------------------------------------------------------------
__global__ __launch_bounds__(256) void ffn2_reduce_kernel(
    const float* __restrict__ pp, const float* __restrict__ bias,
    float* __restrict__ x)
{
    const size_t i = (size_t)(blockIdx.x * 256 + threadIdx.x) * 8;
    const int col = (int)(i % 768);
    const size_t E = (size_t)NTOK * D_SZ;
    float4 s0 = *(const float4*)(x + i);
    float4 s1 = *(const float4*)(x + i + 4);
    float4 b0 = *(const float4*)(bias + col);
    float4 b1 = *(const float4*)(bias + col + 4);
    s0.x += b0.x; s0.y += b0.y; s0.z += b0.z; s0.w += b0.w;
    s1.x += b1.x; s1.y += b1.y; s1.z += b1.z; s1.w += b1.w;
#pragma unroll
    for (int z = 0; z < 4; ++z) {
        float4 p0 = *(const float4*)(pp + z * E + i);
        float4 p1 = *(const float4*)(pp + z * E + i + 4);
        s0.x += p0.x; s0.y += p0.y; s0.z += p0.z; s0.w += p0.w;
        s1.x += p1.x; s1.y += p1.y; s1.z += p1.z; s1.w += p1.w;
    }
    *(float4*)(x + i) = s0;
    *(float4*)(x + i + 4) = s1;
}

// ---------------------------------------------------------------------------
// attn3: kv-split-4 MFMA attention (unchanged)
// ---------------------------------------------------------------------------
__global__ __launch_bounds__(256) void attn3_kernel(
    const unsigned short* __restrict__ Q16, const unsigned short* __restrict__ K16,
    const unsigned short* __restrict__ VT16, unsigned short* __restrict__ ao16)
{
    const int bid = blockIdx.x;
    const int qb = 63 - bid / 24;          // heavy first
    const int bh = bid % 24;
    const int b = bh / H_SZ, h = bh % H_SZ;
    const int tid = threadIdx.x;
    const int w = tid >> 6, lane = tid & 63;
    const int g = lane >> 4, r = lane & 15;

    constexpr int KS = 72;
    __shared__ __align__(16) unsigned short Pl[4][16 * KS];
    __shared__ float so[4][16][66];
    __shared__ float2 sml[4][16];

    const unsigned short* Qb = Q16 + ((size_t)bh << 10) * 64;
    const unsigned short* Kb = K16 + ((size_t)bh << 10) * 64;
    const unsigned short* Vb = VT16 + ((size_t)bh << 6) * 1024;

    bf16x8 qf[2];
    qf[0] = *(const bf16x8*)&Qb[(qb * 16 + r) * 64 + 8 * g];
    qf[1] = *(const bf16x8*)&Qb[(qb * 16 + r) * 64 + 32 + 8 * g];

    float m_r = -1e30f, l_r = 0.f;
    f32x4 o[4];
#pragma unroll
    for (int ni = 0; ni < 4; ++ni) o[ni] = (f32x4){0.f, 0.f, 0.f, 0.f};

    const int nch = (qb >> 2) + 1;
    const int qbm = qb & 3;

    for (int c = w; c < nch; c += 4) {
        const bool lastc = (c == nch - 1);
        const int mi_hi = lastc ? qbm : 3;

        f32x4 s[4];
#pragma unroll
        for (int mi = 0; mi < 4; ++mi) s[mi] = (f32x4){0.f, 0.f, 0.f, 0.f};
#pragma unroll
        for (int mi = 0; mi < 4; ++mi) {
            if (mi <= mi_hi) {
#pragma unroll
                for (int ks = 0; ks < 2; ++ks) {
                    bf16x8 af = *(const bf16x8*)&Kb[(c * 64 + 16 * mi + r) * 64 + 32 * ks + 8 * g];
                    s[mi] = __builtin_amdgcn_mfma_f32_16x16x32_bf16(af, qf[ks], s[mi], 0, 0, 0);
                }
            }
        }

        float mx = -1e30f;
#pragma unroll
        for (int mi = 0; mi < 4; ++mi) {
            if (mi <= mi_hi) {
#pragma unroll
                for (int i = 0; i < 4; ++i) mx = fmaxf(mx, s[mi][i]);
            }
        }
        mx = fmaxf(mx, __shfl_xor(mx, 16));
        mx = fmaxf(mx, __shfl_xor(mx, 32));
        float m_new = fmaxf(m_r, mx);
        float corr = __expf(m_r - m_new);

        float p[4][4];
        float psum = 0.f;
#pragma unroll
        for (int mi = 0; mi < 4; ++mi) {
#pragma unroll
            for (int i = 0; i < 4; ++i) {
                float pv = (mi <= mi_hi) ? __expf(s[mi][i] - m_new) : 0.f;
                p[mi][i] = pv;
                psum += pv;
            }
        }
        psum += __shfl_xor(psum, 16);
        psum += __shfl_xor(psum, 32);
        l_r = l_r * corr + psum;
        m_r = m_new;

#pragma unroll
        for (int mi = 0; mi < 4; ++mi) {
            B4 t;
            t.h[0] = __float22bfloat162_rn(float2{p[mi][0], p[mi][1]});
            t.h[1] = __float22bfloat162_rn(float2{p[mi][2], p[mi][3]});
            *(bf16x4*)&Pl[w][r * KS + 16 * mi + 4 * g] = t.v;
        }

        float co[4];
#pragma unroll
        for (int i = 0; i < 4; ++i) co[i] = __shfl(corr, 4 * g + i);
#pragma unroll
        for (int ni = 0; ni < 4; ++ni)
#pragma unroll
            for (int i = 0; i < 4; ++i) o[ni][i] *= co[i];

#pragma unroll
        for (int ks = 0; ks < 2; ++ks) {
            if (!lastc || 2 * ks <= qbm) {
                bf16x8 pf = *(const bf16x8*)&Pl[w][r * KS + 32 * ks + 8 * g];
#pragma unroll
                for (int ni = 0; ni < 4; ++ni) {
                    bf16x8 vf = *(const bf16x8*)&Vb[(size_t)(r + 16 * ni) * 1024 + c * 64 + 32 * ks + 8 * g];
                    o[ni] = __builtin_amdgcn_mfma_f32_16x16x32_bf16(pf, vf, o[ni], 0, 0, 0);
                }
            }
        }
    }

    if (g == 0) sml[w][r] = float2{m_r, l_r};
#pragma unroll
    for (int ni = 0; ni < 4; ++ni)
#pragma unroll
        for (int i = 0; i < 4; ++i)
            so[w][4 * g + i][r + 16 * ni] = o[ni][i];
    __syncthreads();

#pragma unroll
    for (int j = 0; j < 4; ++j) {
        int e = tid + j * 256;
        int row = e >> 6, col = e & 63;
        float2 p0 = sml[0][row], p1 = sml[1][row], p2 = sml[2][row], p3 = sml[3][row];
        float M = fmaxf(fmaxf(p0.x, p1.x), fmaxf(p2.x, p3.x));
        float w0 = __expf(p0.x - M), w1 = __expf(p1.x - M);
        float w2 = __expf(p2.x - M), w3 = __expf(p3.x - M);
        float L = p0.y * w0 + p1.y * w1 + p2.y * w2 + p3.y * w3;
        float ov = so[0][row][col] * w0 + so[1][row][col] * w1
                 + so[2][row][col] * w2 + so[3][row][col] * w3;
        ao16[(size_t)(b * S_SZ + qb * 16 + row) * D_SZ + h * HD_SZ + col]
            = f2bf(ov / L);
    }
}

// ---------------------------------------------------------------------------
// CE: fallback full-row kernel (when ws too small for fused path)
// ---------------------------------------------------------------------------
__global__ __launch_bounds__(256) void ce2_kernel(
    const float* __restrict__ logits, const int* __restrict__ tgt,
    const int* __restrict__ inp, const float* __restrict__ noise,
    float* __restrict__ ce_row, float* __restrict__ msk_row)
{
    const int row = blockIdx.x;
    const int t = threadIdx.x;
    const float* lr = logits + (size_t)row * V_SZ;
    const float4* lr4 = (const float4*)lr;

    float m = -1e30f, s = 0.f;
    for (int i = t; i < V_SZ / 4; i += 256) {
        float4 v = lr4[i];
        float mx4 = fmaxf(fmaxf(v.x, v.y), fmaxf(v.z, v.w));
        if (mx4 > m) { s *= __expf(m - mx4); m = mx4; }
        s += __expf(v.x - m) + __expf(v.y - m) + __expf(v.z - m) + __expf(v.w - m);
    }

    __shared__ float sm[256], ss[256];
    sm[t] = m; ss[t] = s;
    __syncthreads();
    for (int off = 128; off; off >>= 1) {
        if (t < off) {
            float m2 = fmaxf(sm[t], sm[t + off]);
            ss[t] = ss[t] * __expf(sm[t] - m2) + ss[t + off] * __expf(sm[t + off] - m2);
            sm[t] = m2;
        }
        __syncthreads();
    }
    if (t == 0) {
        float M = sm[0], S = ss[0];
        int tg = tgt[row];
        float ce = -(lr[tg] - M - logf(S));
        int ism = (inp[row] == MASK_ID) ? 1 : 0;
        int b = row / S_SZ;
        ce_row[row] = ism ? (ce / noise[b]) : 0.f;
        msk_row[row] = ism ? 1.f : 0.f;
    }
}

// Reduce the 250 per-block partials per row (fused-CE path)
__global__ __launch_bounds__(64) void ce3_kernel(
    const float2* __restrict__ pm, const float* __restrict__ logits,
    const int* __restrict__ tgt, const int* __restrict__ inp,
    const float* __restrict__ noise, float* __restrict__ ce_row,
    float* __restrict__ msk_row)
{
    const int row = blockIdx.x * 64 + threadIdx.x;
    float m = -1e30f, s = 0.f;
    for (int bb = 0; bb < V_SZ / 128; ++bb) {
        float2 p = pm[(size_t)bb * NTOK + row];
        float M2 = fmaxf(m, p.x);
        s = s * __expf(m - M2) + p.y * __expf(p.x - M2);
        m = M2;
    }
    int tg = tgt[row];
    float lv = logits[(size_t)row * V_SZ + tg];
    float ce = -(lv - m - logf(s));
    int ism = (inp[row] == MASK_ID) ? 1 : 0;
    int b = row / S_SZ;
    ce_row[row] = ism ? (ce / noise[b]) : 0.f;
    msk_row[row] = ism ? 1.f : 0.f;
}

__global__ __launch_bounds__(256) void loss_reduce_kernel(
    const float* __restrict__ ce_row, const float* __restrict__ msk_row,
    float* __restrict__ out0)
{
    const int t = threadIdx.x;
    __shared__ float r1[256], r2[256];
    float s = 0.f, c = 0.f;
    for (int i = t; i < NTOK; i += 256) { s += ce_row[i]; c += msk_row[i]; }
    r1[t] = s; r2[t] = c;
    __syncthreads();
    for (int off = 128; off; off >>= 1) {
        if (t < off) { r1[t] += r1[t + off]; r2[t] += r2[t + off]; }
        __syncthreads();
    }
    if (t == 0) out0[0] = r1[0] / (r2[0] + 1e-8f);
}

// ---------------------------------------------------------------------------
// Host launch
// ---------------------------------------------------------------------------
extern "C" void kernel_launch(void* const* d_in, const int* in_sizes, int n_in,
                              void* d_out, int out_size, void* d_ws, size_t ws_size,
                              hipStream_t stream)
{
    const int*   input_ids  = (const int*)d_in[0];
    const int*   target_ids = (const int*)d_in[1];
    const float* noise      = (const float*)d_in[2];
    const float* emb        = (const float*)d_in[3];
    const float* in_w       = (const float*)d_in[4];
    const float* in_b       = (const float*)d_in[5];
    const float* aow        = (const float*)d_in[6];
    const float* aob        = (const float*)d_in[7];
    const float* ln1w       = (const float*)d_in[8];
    const float* ln1b       = (const float*)d_in[9];
    const float* ln2w       = (const float*)d_in[10];
    const float* ln2b       = (const float*)d_in[11];
    const float* w1         = (const float*)d_in[12];
    const float* b1         = (const float*)d_in[13];
    const float* w2         = (const float*)d_in[14];
    const float* b2         = (const float*)d_in[15];
    const float* projw      = (const float*)d_in[16];
    const float* projb      = (const float*)d_in[17];

    float* out    = (float*)d_out;
    float* logits = out + 1;

    // --- scratch inside d_out (dead before the logits GEMM overwrites) ---
    float* base = out + 4;
    unsigned short* Q16  = (unsigned short*)(base);               // 24x1024x64
    unsigned short* K16  = (unsigned short*)(base + 786432);
    unsigned short* VT16 = (unsigned short*)(base + 1572864);     // 24x64x1024
    unsigned short* ao16 = (unsigned short*)(base + 2359296);     // 2048x768
    unsigned short* mid16= (unsigned short*)(base + 3145728);     // 2048x3072
    float* pp            = base + 6291456;                        // 4x2048x768 f32

    // --- d_ws: x f32 + CE rows + optional xb16 + optional projw16 ---
    float* x       = (float*)d_ws;                 // [2048][768] f32
    float* ce_row  = x + (size_t)NTOK * D_SZ;
    float* msk_row = ce_row + NTOK;
    unsigned short* xb16 = (unsigned short*)(msk_row + NTOK);
    unsigned short* projw16 = xb16 + (size_t)NTOK * D_SZ;
    float2* pm = (float2*)d_ws;                    // CE partials reuse x (dead)
    const bool fA = ws_size >= 9453568ull;                  // room for xb16
    const bool fB = ws_size >= 58605568ull;                 // + projw16

    // --- one-time conversion: only projw (big logits B-side) ---
    if (fB)
        conv_cast_kernel<<<12000, 256, 0, stream>>>(projw, projw16, 3072000);

    embed_rot_kernel<<<NTOK, 256, 0, stream>>>(input_ids, emb, x);

    for (int l = 0; l < L_SZ; ++l) {
        // qkv: full-LN A (ln1), raw f32 in_w, bias=in_b, split epilogue
        mfma_gemm<64, 128, 1, 1, false, false, false, 1><<<dim3(32, 18), 256, 0, stream>>>(
            x, in_w + (size_t)l * 2304 * 768, in_b + l * 2304, nullptr, nullptr,
            Q16, K16, VT16, nullptr, ln1w + l * 768, ln1b + l * 768, NTOK, 2304, 768);
        attn3_kernel<<<1536, 256, 0, stream>>>(Q16, K16, VT16, ao16);
        // attn out: bf16 A (ao16), raw f32 aow, residual into x
        mfma_gemm<64, 64, 2, 0, false, false, false, 1><<<dim3(32, 12), 256, 0, stream>>>(
            ao16, aow + (size_t)l * 768 * 768, aob + l * 768, x, x,
            nullptr, nullptr, nullptr, nullptr, nullptr, nullptr, NTOK, 768, 768);
        // ffn1: full-LN A (ln2), raw f32 w1, GELU -> bf16 mid
        mfma_gemm<64, 128, 1, 2, false, false, false, 1><<<dim3(32, 24), 256, 0, stream>>>(
            x, w1 + (size_t)l * 3072 * 768, b1 + l * 3072, nullptr, (float*)mid16,
            nullptr, nullptr, nullptr, nullptr, ln2w + l * 768, ln2b + l * 768, NTOK, 3072, 768);
        // ffn2: split-K=4 partials, then reduce (bias + residual into x)
        mfma_gemm<64, 64, 2, 3, false, false, false, 4><<<dim3(32, 12, 4), 256, 0, stream>>>(
            mid16, w2 + (size_t)l * 768 * 3072, nullptr, nullptr, pp,
            nullptr, nullptr, nullptr, nullptr, nullptr, nullptr, NTOK, 768, 3072);
        ffn2_reduce_kernel<<<768, 256, 0, stream>>>(pp, b2 + l * 768, x);
    }

    if (fA)
        conv_cast_kernel<<<768, 256, 0, stream>>>(x, xb16, 196608);

    if (fB) {
        mfma_gemm<128, 128, 2, 0, true, true, true, 1><<<dim3(16, 250), 256, 0, stream>>>(
            xb16, projw16, projb, nullptr, logits,
            nullptr, nullptr, nullptr, pm, nullptr, nullptr, NTOK, V_SZ, 768);
        ce3_kernel<<<32, 64, 0, stream>>>(pm, logits, target_ids, input_ids,
                                          noise, ce_row, msk_row);
    } else if (fA) {
        mfma_gemm<128, 128, 2, 0, false, true, true, 1><<<dim3(16, 250), 256, 0, stream>>>(
            xb16, projw, projb, nullptr, logits,
            nullptr, nullptr, nullptr, pm, nullptr, nullptr, NTOK, V_SZ, 768);
        ce3_kernel<<<32, 64, 0, stream>>>(pm, logits, target_ids, input_ids,
                                          noise, ce_row, msk_row);
    } else {
        mfma_gemm<128, 128, 0, 0, false, true, false, 1><<<dim3(16, 250), 256, 0, stream>>>(
            x, projw, projb, nullptr, logits,
            nullptr, nullptr, nullptr, nullptr, nullptr, nullptr, NTOK, V_SZ, 768);
        ce2_kernel<<<NTOK, 256, 0, stream>>>(logits, target_ids, input_ids, noise,
                                             ce_row, msk_row);
    }

    loss_reduce_kernel<<<1, 256, 0, stream>>>(ce_row, msk_row, out);
}

// Round 13
// 2535.018 us; speedup vs baseline: 1.1231x; 1.1231x over previous
//
#include <hip/hip_runtime.h>
#include <hip/hip_bf16.h>
#include <math.h>

// Problem constants
#define V_SZ 32000
#define D_SZ 768
#define H_SZ 12
#define L_SZ 12
#define DF_SZ 3072
#define B_SZ 2
#define S_SZ 1024
#define BS_SZ 16
#define HD_SZ 64
#define MASK_ID 31999
#define NTOK (B_SZ * S_SZ)   // 2048

typedef __attribute__((ext_vector_type(8))) short bf16x8;
typedef __attribute__((ext_vector_type(4))) short bf16x4;
typedef __attribute__((ext_vector_type(4))) float f32x4;

union B8 { bf16x8 v; __hip_bfloat162 h[4]; };
union B4 { bf16x4 v; __hip_bfloat162 h[2]; };
union U4 { ushort4 u; __hip_bfloat162 h[2]; };
union U4E { ushort4 u; unsigned short e[4]; };

__device__ inline unsigned short f2bf(float x) {
    __hip_bfloat16 b = __float2bfloat16(x);
    union { __hip_bfloat16 b; unsigned short u; } c; c.b = b;
    return c.u;
}

// ---------------------------------------------------------------------------
// Weight conversion: fold ln scale into W rows, ln bias into GEMM bias.
// ---------------------------------------------------------------------------
__global__ __launch_bounds__(256) void conv_fold_kernel(
    const float* __restrict__ Wsrc, const float* __restrict__ lnw,
    const float* __restrict__ lnb, const float* __restrict__ bsrc,
    unsigned short* __restrict__ Wdst, float* __restrict__ bdst,
    int rows_per_layer)
{
    const int gw = (blockIdx.x * 256 + threadIdx.x) >> 6;
    const int lane = threadIdx.x & 63;
    const int l = gw / rows_per_layer;
    const float* src = Wsrc + (size_t)gw * D_SZ;
    const float* wv = lnw + l * D_SZ;
    const float* bv = lnb + l * D_SZ;
    unsigned short* dst = Wdst + (size_t)gw * D_SZ;
    float acc = 0.f;
#pragma unroll
    for (int j = 0; j < 3; ++j) {
        int k = lane * 4 + j * 256;
        float4 s = *(const float4*)(src + k);
        float4 w = *(const float4*)(wv + k);
        float4 bb = *(const float4*)(bv + k);
        acc += bb.x * s.x + bb.y * s.y + bb.z * s.z + bb.w * s.w;
        U4 o;
        o.h[0] = __float22bfloat162_rn(float2{s.x * w.x, s.y * w.y});
        o.h[1] = __float22bfloat162_rn(float2{s.z * w.z, s.w * w.w});
        *(ushort4*)(dst + k) = o.u;
    }
#pragma unroll
    for (int off = 32; off; off >>= 1) acc += __shfl_xor(acc, off);
    if (lane == 0) bdst[gw] = bsrc[gw] + acc;
}

// Plain f32 -> bf16 cast, 8 elems/thread
__global__ __launch_bounds__(256) void conv_cast_kernel(
    const float* __restrict__ src, unsigned short* __restrict__ dst, int n8)
{
    int i = blockIdx.x * 256 + threadIdx.x;
    if (i >= n8) return;
    const float* p = src + (size_t)i * 8;
    float4 v0 = *(const float4*)p;
    float4 v1 = *(const float4*)(p + 4);
    B8 r;
    r.h[0] = __float22bfloat162_rn(float2{v0.x, v0.y});
    r.h[1] = __float22bfloat162_rn(float2{v0.z, v0.w});
    r.h[2] = __float22bfloat162_rn(float2{v1.x, v1.y});
    r.h[3] = __float22bfloat162_rn(float2{v1.z, v1.w});
    *(bf16x8*)(dst + (size_t)i * 8) = r.v;
}

// ---------------------------------------------------------------------------
// Embedding gather + rotary
// ---------------------------------------------------------------------------
__global__ __launch_bounds__(256) void embed_rot_kernel(
    const int* __restrict__ ids, const float* __restrict__ emb,
    float* __restrict__ x)
{
    const int tok = blockIdx.x;
    const int s = tok & (S_SZ - 1);
    const int id = ids[tok];
    const float* e = emb + (size_t)id * D_SZ;
    float* xo = x + (size_t)tok * D_SZ;
    const int t = threadIdx.x;

    if (t < 192) {
        float x0 = e[2 * t], x1 = e[2 * t + 1];
        float freq = powf(10000.f, -((float)(2 * t)) / 384.f);
        float ang = (float)s * freq;
        float sn, cs;
        sincosf(ang, &sn, &cs);
        xo[2 * t]     = x0 * cs - x1 * sn;
        xo[2 * t + 1] = x0 * sn + x1 * cs;
    }
    for (int ch = 384 + t; ch < D_SZ; ch += 256) xo[ch] = e[ch];
}

// ---------------------------------------------------------------------------
// MFMA bf16 GEMM, single-step prefetch, REG-STAGED all sides (R10-best).
// LDS layout: linear 16B slots. Slot c holds (row = c>>2,
// ksg = ((c&3) + (c>>3)) & 3) -- K-subchunk swizzled WITHIN each row so:
//  * staging global reads stay coalesced (4 lanes cover one row's 64B line)
//  * staging LDS writes land at consecutive slots (conflict-free)
//  * fragment reads (row', kgrp) hit slot row'*4 + ((kgrp-(row'>>1))&3)
//    -> slot mod 8 covers all 8 values, 2 lanes each -> conflict-free.
//  AM: 0 f32 A; 1 f32 A + fused LN (BM==64); 2 bf16 A
//  CM: 0 f32 C (+Res); 1 qkv split epilogue; 2 GELU -> bf16 C;
//      3 raw f32 partial (split-K, no bias/res)
//  WB16: W bf16.  XSWZ: XCD swizzle.  CEP: per-block CE partials.
//  SPLITK: K-chunks along blockIdx.z.
// ---------------------------------------------------------------------------
template<int BM, int BN, int AM, int CM, bool WB16, bool XSWZ, bool CEP, int SPLITK>
__global__ __launch_bounds__(256) void mfma_gemm(
    const void* __restrict__ Av, const void* __restrict__ Wv,
    const float* __restrict__ bias, const float* __restrict__ Res,
    float* __restrict__ C,
    unsigned short* __restrict__ qp, unsigned short* __restrict__ kp,
    unsigned short* __restrict__ vp, float2* __restrict__ pm,
    int M, int N, int K)
{
    constexpr int MR = BM / 32;
    constexpr int NR = BN / 32;
    constexpr int ACH = BM * 4 / 256;         // 16B slots per thread (A)
    constexpr int BCH = BN * 4 / 256;

    __shared__ __align__(16) unsigned short As[2][BM * 32];
    __shared__ __align__(16) unsigned short Bs[2][BN * 32];
    __shared__ float smean[AM == 1 ? BM : 1];
    __shared__ float srstd[AM == 1 ? BM : 1];

    const int tid = threadIdx.x;
    const int lane = tid & 63;
    const int wave = tid >> 6;
    const int wrow0 = (wave >> 1) * (BM / 2);
    const int wcol0 = (wave & 1) * (BN / 2);
    const int kgrp = lane >> 4;
    const int rc = lane & 15;
    // in-row K-subchunk swizzle offset for fragment reads (shorts)
    const int dsw = ((kgrp - (rc >> 1)) & 3) * 8;

    int m0, n0;
    if constexpr (XSWZ) {
        int id = blockIdx.y * gridDim.x + blockIdx.x;
        int cpx = (gridDim.x * gridDim.y) >> 3;
        int swz = (id & 7) * cpx + (id >> 3);
        m0 = (swz % gridDim.x) * BM;
        n0 = (swz / gridDim.x) * BN;
    } else {
        m0 = blockIdx.x * BM;
        n0 = blockIdx.y * BN;
    }
    const int kdiv = K / SPLITK;
    const int kbase = (SPLITK > 1) ? blockIdx.z * kdiv : 0;

    if constexpr (AM == 1) {
        const float* A = (const float*)Av;
        const int row = tid >> 2, q = tid & 3;
        const float* xr = A + (size_t)(m0 + row) * K + q * (K >> 2);
        float sum = 0.f, ss = 0.f;
        for (int j = 0; j < (K >> 4); ++j) {
            float4 v = *(const float4*)(xr + j * 4);
            sum += v.x + v.y + v.z + v.w;
            ss += v.x * v.x + v.y * v.y + v.z * v.z + v.w * v.w;
        }
        sum += __shfl_xor(sum, 1); sum += __shfl_xor(sum, 2);
        ss  += __shfl_xor(ss, 1);  ss  += __shfl_xor(ss, 2);
        float mean = sum * (1.f / (float)K);
        float var = ss * (1.f / (float)K) - mean * mean;
        if (q == 0) { smean[row] = mean; srstd[row] = rsqrtf(var + 1e-5f); }
        __syncthreads();
    }

    f32x4 acc[MR][NR];
#pragma unroll
    for (int i = 0; i < MR; ++i)
#pragma unroll
        for (int j = 0; j < NR; ++j) acc[i][j] = (f32x4){0.f, 0.f, 0.f, 0.f};

    float areg[(AM != 2) ? ACH : 1][8];
    bf16x8 areg16[(AM == 2) ? ACH : 1];
    float bregf[WB16 ? 1 : BCH][8];
    bf16x8 breg16[WB16 ? BCH : 1];

    // ---- A staging: slot c = tid + i*256; row = c>>2, ksg swizzled ----
    auto load_a = [&](int k0) {
#pragma unroll
        for (int i = 0; i < ACH; ++i) {
            int c = tid + i * 256;
            int row = c >> 2, ksg = ((c & 3) + (c >> 3)) & 3;
            if constexpr (AM == 2) {
                const unsigned short* A16 = (const unsigned short*)Av;
                areg16[i] = *(const bf16x8*)(A16 + (size_t)(m0 + row) * K + k0 + ksg * 8);
            } else {
                const float* p = (const float*)Av + (size_t)(m0 + row) * K + k0 + ksg * 8;
                float4 v0 = *(const float4*)p;
                float4 v1 = *(const float4*)(p + 4);
                areg[i][0] = v0.x; areg[i][1] = v0.y; areg[i][2] = v0.z; areg[i][3] = v0.w;
                areg[i][4] = v1.x; areg[i][5] = v1.y; areg[i][6] = v1.z; areg[i][7] = v1.w;
            }
        }
    };
    auto write_a = [&](int buf) {
#pragma unroll
        for (int i = 0; i < ACH; ++i) {
            int c = tid + i * 256;
            if constexpr (AM == 2) {
                *(bf16x8*)&As[buf][c * 8] = areg16[i];
            } else {
                int row = c >> 2;
                float sc = 1.f, sh = 0.f;
                if constexpr (AM == 1) { sc = srstd[row]; sh = -smean[row] * sc; }
                B8 r;
                r.h[0] = __float22bfloat162_rn(float2{fmaf(areg[i][0], sc, sh), fmaf(areg[i][1], sc, sh)});
                r.h[1] = __float22bfloat162_rn(float2{fmaf(areg[i][2], sc, sh), fmaf(areg[i][3], sc, sh)});
                r.h[2] = __float22bfloat162_rn(float2{fmaf(areg[i][4], sc, sh), fmaf(areg[i][5], sc, sh)});
                r.h[3] = __float22bfloat162_rn(float2{fmaf(areg[i][6], sc, sh), fmaf(areg[i][7], sc, sh)});
                *(bf16x8*)&As[buf][c * 8] = r.v;
            }
        }
    };

    // ---- B staging ----
    auto load_b = [&](int k0) {
#pragma unroll
        for (int i = 0; i < BCH; ++i) {
            int c = tid + i * 256;
            int row = c >> 2, ksg = ((c & 3) + (c >> 3)) & 3;
            if constexpr (WB16) {
                const unsigned short* W16 = (const unsigned short*)Wv;
                breg16[i] = *(const bf16x8*)(W16 + (size_t)(n0 + row) * K + k0 + ksg * 8);
            } else {
                const float* p = (const float*)Wv + (size_t)(n0 + row) * K + k0 + ksg * 8;
                float4 v0 = *(const float4*)p;
                float4 v1 = *(const float4*)(p + 4);
                bregf[i][0] = v0.x; bregf[i][1] = v0.y; bregf[i][2] = v0.z; bregf[i][3] = v0.w;
                bregf[i][4] = v1.x; bregf[i][5] = v1.y; bregf[i][6] = v1.z; bregf[i][7] = v1.w;
            }
        }
    };
    auto write_b = [&](int buf) {
#pragma unroll
        for (int i = 0; i < BCH; ++i) {
            int c = tid + i * 256;
            if constexpr (WB16) {
                *(bf16x8*)&Bs[buf][c * 8] = breg16[i];
            } else {
                B8 r;
                r.h[0] = __float22bfloat162_rn(float2{bregf[i][0], bregf[i][1]});
                r.h[1] = __float22bfloat162_rn(float2{bregf[i][2], bregf[i][3]});
                r.h[2] = __float22bfloat162_rn(float2{bregf[i][4], bregf[i][5]});
                r.h[3] = __float22bfloat162_rn(float2{bregf[i][6], bregf[i][7]});
                *(bf16x8*)&Bs[buf][c * 8] = r.v;
            }
        }
    };

    auto compute = [&](int buf) {
        bf16x8 af[MR], bf[NR];
#pragma unroll
        for (int mi = 0; mi < MR; ++mi)
            af[mi] = *(const bf16x8*)&As[buf][(wrow0 + mi * 16 + rc) * 32 + dsw];
#pragma unroll
        for (int ni = 0; ni < NR; ++ni)
            bf[ni] = *(const bf16x8*)&Bs[buf][(wcol0 + ni * 16 + rc) * 32 + dsw];
#pragma unroll
        for (int mi = 0; mi < MR; ++mi)
#pragma unroll
            for (int ni = 0; ni < NR; ++ni)
                acc[mi][ni] = __builtin_amdgcn_mfma_f32_16x16x32_bf16(
                    af[mi], bf[ni], acc[mi][ni], 0, 0, 0);
    };

    // ---- prologue: stage K-step kbase into buf 0 ----
    load_a(kbase);
    load_b(kbase);
    write_a(0);
    write_b(0);
    __syncthreads();

    const int nk = kdiv >> 5;
    int cur = 0;
    for (int s = 0; s < nk; ++s) {
        const bool more = (s + 1 < nk);
        const int k1 = kbase + ((s + 1) << 5);
        if (more) { load_a(k1); load_b(k1); }
        compute(cur);
        if (more) { write_a(cur ^ 1); write_b(cur ^ 1); }
        __syncthreads();
        cur ^= 1;
    }

    // ---- epilogue ----
#pragma unroll
    for (int mi = 0; mi < MR; ++mi) {
#pragma unroll
        for (int ni = 0; ni < NR; ++ni) {
            const int col = n0 + wcol0 + ni * 16 + rc;
            const int rbase = m0 + wrow0 + mi * 16 + kgrp * 4;
            if constexpr (CM == 1) {
                float bv = bias[col];
                const int region = col / 768;
                const int c768 = col - region * 768;
                const int hh = c768 >> 6, d = c768 & 63;
                const int bb = rbase >> 10, s0 = rbase & 1023;
                const int bh = bb * H_SZ + hh;
                if (region == 0) {
#pragma unroll
                    for (int i = 0; i < 4; ++i)
                        qp[((size_t)(bh << 10) + s0 + i) * 64 + d]
                            = f2bf((acc[mi][ni][i] + bv) * 0.125f);
                } else if (region == 1) {
#pragma unroll
                    for (int i = 0; i < 4; ++i)
                        kp[((size_t)(bh << 10) + s0 + i) * 64 + d]
                            = f2bf(acc[mi][ni][i] + bv);
                } else {
                    U4E t4;
#pragma unroll
                    for (int i = 0; i < 4; ++i) t4.e[i] = f2bf(acc[mi][ni][i] + bv);
                    *(ushort4*)&vp[(((size_t)bh * 64 + d) << 10) + s0] = t4.u;
                }
            } else if constexpr (CM == 2) {
                float bv = bias[col];
                unsigned short* C16 = (unsigned short*)C;
#pragma unroll
                for (int i = 0; i < 4; ++i) {
                    float v = acc[mi][ni][i] + bv;
                    v = 0.5f * v * (1.f + erff(v * 0.70710678118654752f));
                    C16[(size_t)(rbase + i) * N + col] = f2bf(v);
                }
            } else if constexpr (CM == 3) {
                float* P = C + (size_t)blockIdx.z * ((size_t)M * N);
                size_t basei = (size_t)rbase * N + col;
#pragma unroll
                for (int i = 0; i < 4; ++i)
                    P[basei + (size_t)i * N] = acc[mi][ni][i];
            } else {
                float bv = bias ? bias[col] : 0.f;
                size_t basei = (size_t)rbase * N + col;
#pragma unroll
                for (int i = 0; i < 4; ++i) {
                    float v = acc[mi][ni][i] + bv;
                    size_t idx = basei + (size_t)i * N;
                    if (Res) v += Res[idx];
                    C[idx] = v;
                }
            }
        }
    }

    // ---- fused CE partials (per-block row max & sumexp over BN cols) ----
    if constexpr (CEP) {
        float2 (*sce)[2] = (float2 (*)[2])As;    // reuse LDS (post-barrier)
        float bvv[NR];
#pragma unroll
        for (int ni = 0; ni < NR; ++ni) bvv[ni] = bias[n0 + wcol0 + ni * 16 + rc];
#pragma unroll
        for (int mi = 0; mi < MR; ++mi) {
#pragma unroll
            for (int i = 0; i < 4; ++i) {
                float vmax = -1e30f;
#pragma unroll
                for (int ni = 0; ni < NR; ++ni)
                    vmax = fmaxf(vmax, acc[mi][ni][i] + bvv[ni]);
                vmax = fmaxf(vmax, __shfl_xor(vmax, 1));
                vmax = fmaxf(vmax, __shfl_xor(vmax, 2));
                vmax = fmaxf(vmax, __shfl_xor(vmax, 4));
                vmax = fmaxf(vmax, __shfl_xor(vmax, 8));
                float ssum = 0.f;
#pragma unroll
                for (int ni = 0; ni < NR; ++ni)
                    ssum += __expf(acc[mi][ni][i] + bvv[ni] - vmax);
                ssum += __shfl_xor(ssum, 1);
                ssum += __shfl_xor(ssum, 2);
                ssum += __shfl_xor(ssum, 4);
                ssum += __shfl_xor(ssum, 8);
                if (rc == 0)
                    sce[wrow0 + mi * 16 + kgrp * 4 + i][wave & 1] = float2{vmax, ssum};
            }
        }
        __syncthreads();
        if (tid < BM) {
            float2 a = sce[tid][0], b2 = sce[tid][1];
            float Mv = fmaxf(a.x, b2.x);
            float Sv = a.y * __expf(a.x - Mv) + b2.y * __expf(b2.x - Mv);
            pm[(size_t)(n0 >> 7) * NTOK + m0 + tid] = float2{Mv, Sv};
        }
    }
}

// ---------------------------------------------------------------------------
// ffn2 split-K=2 reduce: x += b2 + pp[0] + pp[1]   (8 f32 per thread)
// ---------------------------------------------------------------------------
__global__ __launch_bounds__(256) void ffn2_reduce_kernel(
    const float* __restrict__ pp, const float* __restrict__ bias,
    float* __restrict__ x)
{
    const size_t i = (size_t)(blockIdx.x * 256 + threadIdx.x) * 8;
    const int col = (int)(i % 768);
    const size_t E = (size_t)NTOK * D_SZ;
    float4 s0 = *(const float4*)(x + i);
    float4 s1 = *(const float4*)(x + i + 4);
    float4 b0 = *(const float4*)(bias + col);
    float4 b1 = *(const float4*)(bias + col + 4);
    s0.x += b0.x; s0.y += b0.y; s0.z += b0.z; s0.w += b0.w;
    s1.x += b1.x; s1.y += b1.y; s1.z += b1.z; s1.w += b1.w;
#pragma unroll
    for (int z = 0; z < 2; ++z) {
        float4 p0 = *(const float4*)(pp + z * E + i);
        float4 p1 = *(const float4*)(pp + z * E + i + 4);
        s0.x += p0.x; s0.y += p0.y; s0.z += p0.z; s0.w += p0.w;
        s1.x += p1.x; s1.y += p1.y; s1.z += p1.z; s1.w += p1.w;
    }
    *(float4*)(x + i) = s0;
    *(float4*)(x + i + 4) = s1;
}

// ---------------------------------------------------------------------------
// attn3: kv-split-4 MFMA attention (unchanged)
// ---------------------------------------------------------------------------
__global__ __launch_bounds__(256) void attn3_kernel(
    const unsigned short* __restrict__ Q16, const unsigned short* __restrict__ K16,
    const unsigned short* __restrict__ VT16, unsigned short* __restrict__ ao16)
{
    const int bid = blockIdx.x;
    const int qb = 63 - bid / 24;          // heavy first
    const int bh = bid % 24;
    const int b = bh / H_SZ, h = bh % H_SZ;
    const int tid = threadIdx.x;
    const int w = tid >> 6, lane = tid & 63;
    const int g = lane >> 4, r = lane & 15;

    constexpr int KS = 72;
    __shared__ __align__(16) unsigned short Pl[4][16 * KS];
    __shared__ float so[4][16][66];
    __shared__ float2 sml[4][16];

    const unsigned short* Qb = Q16 + ((size_t)bh << 10) * 64;
    const unsigned short* Kb = K16 + ((size_t)bh << 10) * 64;
    const unsigned short* Vb = VT16 + ((size_t)bh << 6) * 1024;

    bf16x8 qf[2];
    qf[0] = *(const bf16x8*)&Qb[(qb * 16 + r) * 64 + 8 * g];
    qf[1] = *(const bf16x8*)&Qb[(qb * 16 + r) * 64 + 32 + 8 * g];

    float m_r = -1e30f, l_r = 0.f;
    f32x4 o[4];
#pragma unroll
    for (int ni = 0; ni < 4; ++ni) o[ni] = (f32x4){0.f, 0.f, 0.f, 0.f};

    const int nch = (qb >> 2) + 1;
    const int qbm = qb & 3;

    for (int c = w; c < nch; c += 4) {
        const bool lastc = (c == nch - 1);
        const int mi_hi = lastc ? qbm : 3;

        f32x4 s[4];
#pragma unroll
        for (int mi = 0; mi < 4; ++mi) s[mi] = (f32x4){0.f, 0.f, 0.f, 0.f};
#pragma unroll
        for (int mi = 0; mi < 4; ++mi) {
            if (mi <= mi_hi) {
#pragma unroll
                for (int ks = 0; ks < 2; ++ks) {
                    bf16x8 af = *(const bf16x8*)&Kb[(c * 64 + 16 * mi + r) * 64 + 32 * ks + 8 * g];
                    s[mi] = __builtin_amdgcn_mfma_f32_16x16x32_bf16(af, qf[ks], s[mi], 0, 0, 0);
                }
            }
        }

        float mx = -1e30f;
#pragma unroll
        for (int mi = 0; mi < 4; ++mi) {
            if (mi <= mi_hi) {
#pragma unroll
                for (int i = 0; i < 4; ++i) mx = fmaxf(mx, s[mi][i]);
            }
        }
        mx = fmaxf(mx, __shfl_xor(mx, 16));
        mx = fmaxf(mx, __shfl_xor(mx, 32));
        float m_new = fmaxf(m_r, mx);
        float corr = __expf(m_r - m_new);

        float p[4][4];
        float psum = 0.f;
#pragma unroll
        for (int mi = 0; mi < 4; ++mi) {
#pragma unroll
            for (int i = 0; i < 4; ++i) {
                float pv = (mi <= mi_hi) ? __expf(s[mi][i] - m_new) : 0.f;
                p[mi][i] = pv;
                psum += pv;
            }
        }
        psum += __shfl_xor(psum, 16);
        psum += __shfl_xor(psum, 32);
        l_r = l_r * corr + psum;
        m_r = m_new;

#pragma unroll
        for (int mi = 0; mi < 4; ++mi) {
            B4 t;
            t.h[0] = __float22bfloat162_rn(float2{p[mi][0], p[mi][1]});
            t.h[1] = __float22bfloat162_rn(float2{p[mi][2], p[mi][3]});
            *(bf16x4*)&Pl[w][r * KS + 16 * mi + 4 * g] = t.v;
        }

        float co[4];
#pragma unroll
        for (int i = 0; i < 4; ++i) co[i] = __shfl(corr, 4 * g + i);
#pragma unroll
        for (int ni = 0; ni < 4; ++ni)
#pragma unroll
            for (int i = 0; i < 4; ++i) o[ni][i] *= co[i];

#pragma unroll
        for (int ks = 0; ks < 2; ++ks) {
            if (!lastc || 2 * ks <= qbm) {
                bf16x8 pf = *(const bf16x8*)&Pl[w][r * KS + 32 * ks + 8 * g];
#pragma unroll
                for (int ni = 0; ni < 4; ++ni) {
                    bf16x8 vf = *(const bf16x8*)&Vb[(size_t)(r + 16 * ni) * 1024 + c * 64 + 32 * ks + 8 * g];
                    o[ni] = __builtin_amdgcn_mfma_f32_16x16x32_bf16(pf, vf, o[ni], 0, 0, 0);
                }
            }
        }
    }

    if (g == 0) sml[w][r] = float2{m_r, l_r};
#pragma unroll
    for (int ni = 0; ni < 4; ++ni)
#pragma unroll
        for (int i = 0; i < 4; ++i)
            so[w][4 * g + i][r + 16 * ni] = o[ni][i];
    __syncthreads();

#pragma unroll
    for (int j = 0; j < 4; ++j) {
        int e = tid + j * 256;
        int row = e >> 6, col = e & 63;
        float2 p0 = sml[0][row], p1 = sml[1][row], p2 = sml[2][row], p3 = sml[3][row];
        float M = fmaxf(fmaxf(p0.x, p1.x), fmaxf(p2.x, p3.x));
        float w0 = __expf(p0.x - M), w1 = __expf(p1.x - M);
        float w2 = __expf(p2.x - M), w3 = __expf(p3.x - M);
        float L = p0.y * w0 + p1.y * w1 + p2.y * w2 + p3.y * w3;
        float ov = so[0][row][col] * w0 + so[1][row][col] * w1
                 + so[2][row][col] * w2 + so[3][row][col] * w3;
        ao16[(size_t)(b * S_SZ + qb * 16 + row) * D_SZ + h * HD_SZ + col]
            = f2bf(ov / L);
    }
}

// ---------------------------------------------------------------------------
// CE: fallback full-row kernel (when ws too small for fused path)
// ---------------------------------------------------------------------------
__global__ __launch_bounds__(256) void ce2_kernel(
    const float* __restrict__ logits, const int* __restrict__ tgt,
    const int* __restrict__ inp, const float* __restrict__ noise,
    float* __restrict__ ce_row, float* __restrict__ msk_row)
{
    const int row = blockIdx.x;
    const int t = threadIdx.x;
    const float* lr = logits + (size_t)row * V_SZ;
    const float4* lr4 = (const float4*)lr;

    float m = -1e30f, s = 0.f;
    for (int i = t; i < V_SZ / 4; i += 256) {
        float4 v = lr4[i];
        float mx4 = fmaxf(fmaxf(v.x, v.y), fmaxf(v.z, v.w));
        if (mx4 > m) { s *= __expf(m - mx4); m = mx4; }
        s += __expf(v.x - m) + __expf(v.y - m) + __expf(v.z - m) + __expf(v.w - m);
    }

    __shared__ float sm[256], ss[256];
    sm[t] = m; ss[t] = s;
    __syncthreads();
    for (int off = 128; off; off >>= 1) {
        if (t < off) {
            float m2 = fmaxf(sm[t], sm[t + off]);
            ss[t] = ss[t] * __expf(sm[t] - m2) + ss[t + off] * __expf(sm[t + off] - m2);
            sm[t] = m2;
        }
        __syncthreads();
    }
    if (t == 0) {
        float M = sm[0], S = ss[0];
        int tg = tgt[row];
        float ce = -(lr[tg] - M - logf(S));
        int ism = (inp[row] == MASK_ID) ? 1 : 0;
        int b = row / S_SZ;
        ce_row[row] = ism ? (ce / noise[b]) : 0.f;
        msk_row[row] = ism ? 1.f : 0.f;
    }
}

// Reduce the 250 per-block partials per row (fused-CE path)
__global__ __launch_bounds__(64) void ce3_kernel(
    const float2* __restrict__ pm, const float* __restrict__ logits,
    const int* __restrict__ tgt, const int* __restrict__ inp,
    const float* __restrict__ noise, float* __restrict__ ce_row,
    float* __restrict__ msk_row)
{
    const int row = blockIdx.x * 64 + threadIdx.x;
    float m = -1e30f, s = 0.f;
    for (int bb = 0; bb < V_SZ / 128; ++bb) {
        float2 p = pm[(size_t)bb * NTOK + row];
        float M2 = fmaxf(m, p.x);
        s = s * __expf(m - M2) + p.y * __expf(p.x - M2);
        m = M2;
    }
    int tg = tgt[row];
    float lv = logits[(size_t)row * V_SZ + tg];
    float ce = -(lv - m - logf(s));
    int ism = (inp[row] == MASK_ID) ? 1 : 0;
    int b = row / S_SZ;
    ce_row[row] = ism ? (ce / noise[b]) : 0.f;
    msk_row[row] = ism ? 1.f : 0.f;
}

__global__ __launch_bounds__(256) void loss_reduce_kernel(
    const float* __restrict__ ce_row, const float* __restrict__ msk_row,
    float* __restrict__ out0)
{
    const int t = threadIdx.x;
    __shared__ float r1[256], r2[256];
    float s = 0.f, c = 0.f;
    for (int i = t; i < NTOK; i += 256) { s += ce_row[i]; c += msk_row[i]; }
    r1[t] = s; r2[t] = c;
    __syncthreads();
    for (int off = 128; off; off >>= 1) {
        if (t < off) { r1[t] += r1[t + off]; r2[t] += r2[t + off]; }
        __syncthreads();
    }
    if (t == 0) out0[0] = r1[0] / (r2[0] + 1e-8f);
}

// ---------------------------------------------------------------------------
// Host launch
// ---------------------------------------------------------------------------
extern "C" void kernel_launch(void* const* d_in, const int* in_sizes, int n_in,
                              void* d_out, int out_size, void* d_ws, size_t ws_size,
                              hipStream_t stream)
{
    const int*   input_ids  = (const int*)d_in[0];
    const int*   target_ids = (const int*)d_in[1];
    const float* noise      = (const float*)d_in[2];
    const float* emb        = (const float*)d_in[3];
    const float* in_w       = (const float*)d_in[4];
    const float* in_b       = (const float*)d_in[5];
    const float* aow        = (const float*)d_in[6];
    const float* aob        = (const float*)d_in[7];
    const float* ln1w       = (const float*)d_in[8];
    const float* ln1b       = (const float*)d_in[9];
    const float* ln2w       = (const float*)d_in[10];
    const float* ln2b       = (const float*)d_in[11];
    const float* w1         = (const float*)d_in[12];
    const float* b1         = (const float*)d_in[13];
    const float* w2         = (const float*)d_in[14];
    const float* b2         = (const float*)d_in[15];
    const float* projw      = (const float*)d_in[16];
    const float* projb      = (const float*)d_in[17];

    float* out    = (float*)d_out;
    float* logits = out + 1;

    // --- scratch inside d_out (dead before the logits GEMM overwrites) ---
    float* base = out + 4;
    unsigned short* wq16 = (unsigned short*)(base);               // 12x2304x768
    unsigned short* wa16 = (unsigned short*)(base + 10616832);    // 12x768x768
    unsigned short* w116 = (unsigned short*)(base + 14155776);    // 12x3072x768
    unsigned short* w216 = (unsigned short*)(base + 28311552);    // 12x768x3072
    float* qkvb2 = base + 42467328;                               // 12x2304
    float* b1b2  = qkvb2 + 27648;                                 // 12x3072
    unsigned short* Q16  = (unsigned short*)(base + 42531840);    // 24x1024x64
    unsigned short* K16  = (unsigned short*)(base + 43318272);
    unsigned short* VT16 = (unsigned short*)(base + 44104704);    // 24x64x1024
    unsigned short* ao16 = (unsigned short*)(base + 44891136);    // 2048x768
    unsigned short* mid16= (unsigned short*)(base + 45677568);    // 2048x3072
    float* pp            = base + 48823296;                       // 2x2048x768 f32
    // end: 4 + 51,969,024 < 65,536,001 ✓

    // --- d_ws: x f32 + CE rows + optional xb16 + optional projw16 ---
    float* x       = (float*)d_ws;                 // [2048][768] f32
    float* ce_row  = x + (size_t)NTOK * D_SZ;
    float* msk_row = ce_row + NTOK;
    unsigned short* xb16 = (unsigned short*)(msk_row + NTOK);
    unsigned short* projw16 = xb16 + (size_t)NTOK * D_SZ;
    float2* pm = (float2*)d_ws;                    // CE partials reuse x (dead)
    const bool fA = ws_size >= 9453568ull;                  // room for xb16
    const bool fB = ws_size >= 58605568ull;                 // + projw16

    // --- one-time weight conversions ---
    conv_fold_kernel<<<6912, 256, 0, stream>>>(in_w, ln1w, ln1b, in_b, wq16, qkvb2, 2304);
    conv_fold_kernel<<<9216, 256, 0, stream>>>(w1, ln2w, ln2b, b1, w116, b1b2, 3072);
    conv_cast_kernel<<<3456, 256, 0, stream>>>(aow, wa16, 884736);
    conv_cast_kernel<<<13824, 256, 0, stream>>>(w2, w216, 3538944);
    if (fB)
        conv_cast_kernel<<<12000, 256, 0, stream>>>(projw, projw16, 3072000);

    embed_rot_kernel<<<NTOK, 256, 0, stream>>>(input_ids, emb, x);

    for (int l = 0; l < L_SZ; ++l) {
        mfma_gemm<64, 128, 1, 1, true, false, false, 1><<<dim3(32, 18), 256, 0, stream>>>(
            x, wq16 + (size_t)l * 1769472, qkvb2 + l * 2304, nullptr, nullptr,
            Q16, K16, VT16, nullptr, NTOK, 2304, 768);
        attn3_kernel<<<1536, 256, 0, stream>>>(Q16, K16, VT16, ao16);
        mfma_gemm<64, 64, 2, 0, true, false, false, 1><<<dim3(32, 12), 256, 0, stream>>>(
            ao16, wa16 + (size_t)l * 589824, aob + l * D_SZ, x, x,
            nullptr, nullptr, nullptr, nullptr, NTOK, 768, 768);
        mfma_gemm<64, 128, 1, 2, true, false, false, 1><<<dim3(32, 24), 256, 0, stream>>>(
            x, w116 + (size_t)l * 2359296, b1b2 + l * 3072, nullptr, (float*)mid16,
            nullptr, nullptr, nullptr, nullptr, NTOK, 3072, 768);
        // ffn2: split-K=2 (bf16 W kept), partials -> pp, reduce adds bias+res
        mfma_gemm<64, 64, 2, 3, true, false, false, 2><<<dim3(32, 12, 2), 256, 0, stream>>>(
            mid16, w216 + (size_t)l * 2359296, nullptr, nullptr, pp,
            nullptr, nullptr, nullptr, nullptr, NTOK, 768, 3072);
        ffn2_reduce_kernel<<<768, 256, 0, stream>>>(pp, b2 + l * D_SZ, x);
    }

    if (fA)
        conv_cast_kernel<<<768, 256, 0, stream>>>(x, xb16, 196608);

    if (fB) {
        mfma_gemm<128, 128, 2, 0, true, true, true, 1><<<dim3(16, 250), 256, 0, stream>>>(
            xb16, projw16, projb, nullptr, logits,
            nullptr, nullptr, nullptr, pm, NTOK, V_SZ, 768);
        ce3_kernel<<<32, 64, 0, stream>>>(pm, logits, target_ids, input_ids,
                                          noise, ce_row, msk_row);
    } else if (fA) {
        mfma_gemm<128, 128, 2, 0, false, true, true, 1><<<dim3(16, 250), 256, 0, stream>>>(
            xb16, projw, projb, nullptr, logits,
            nullptr, nullptr, nullptr, pm, NTOK, V_SZ, 768);
        ce3_kernel<<<32, 64, 0, stream>>>(pm, logits, target_ids, input_ids,
                                          noise, ce_row, msk_row);
    } else {
        mfma_gemm<128, 128, 0, 0, false, true, false, 1><<<dim3(16, 250), 256, 0, stream>>>(
            x, projw, projb, nullptr, logits,
            nullptr, nullptr, nullptr, nullptr, NTOK, V_SZ, 768);
        ce2_kernel<<<NTOK, 256, 0, stream>>>(logits, target_ids, input_ids, noise,
                                             ce_row, msk_row);
    }

    loss_reduce_kernel<<<1, 256, 0, stream>>>(ce_row, msk_row, out);
}

// Round 14
// 2199.459 us; speedup vs baseline: 1.2945x; 1.1526x over previous
//
#include <hip/hip_runtime.h>
#include <hip/hip_bf16.h>
#include <math.h>

// Problem constants
#define V_SZ 32000
#define D_SZ 768
#define H_SZ 12
#define L_SZ 12
#define DF_SZ 3072
#define B_SZ 2
#define S_SZ 1024
#define BS_SZ 16
#define HD_SZ 64
#define MASK_ID 31999
#define NTOK (B_SZ * S_SZ)   // 2048

typedef __attribute__((ext_vector_type(8))) short bf16x8;
typedef __attribute__((ext_vector_type(4))) short bf16x4;
typedef __attribute__((ext_vector_type(4))) float f32x4;

union B8 { bf16x8 v; __hip_bfloat162 h[4]; };
union B4 { bf16x4 v; __hip_bfloat162 h[2]; };
union U4 { ushort4 u; __hip_bfloat162 h[2]; };
union U4E { ushort4 u; unsigned short e[4]; };

__device__ inline unsigned short f2bf(float x) {
    __hip_bfloat16 b = __float2bfloat16(x);
    union { __hip_bfloat16 b; unsigned short u; } c; c.b = b;
    return c.u;
}

// ---------------------------------------------------------------------------
// Weight conversion: fold ln scale into W rows, ln bias into GEMM bias.
// ---------------------------------------------------------------------------
__global__ __launch_bounds__(256) void conv_fold_kernel(
    const float* __restrict__ Wsrc, const float* __restrict__ lnw,
    const float* __restrict__ lnb, const float* __restrict__ bsrc,
    unsigned short* __restrict__ Wdst, float* __restrict__ bdst,
    int rows_per_layer)
{
    const int gw = (blockIdx.x * 256 + threadIdx.x) >> 6;
    const int lane = threadIdx.x & 63;
    const int l = gw / rows_per_layer;
    const float* src = Wsrc + (size_t)gw * D_SZ;
    const float* wv = lnw + l * D_SZ;
    const float* bv = lnb + l * D_SZ;
    unsigned short* dst = Wdst + (size_t)gw * D_SZ;
    float acc = 0.f;
#pragma unroll
    for (int j = 0; j < 3; ++j) {
        int k = lane * 4 + j * 256;
        float4 s = *(const float4*)(src + k);
        float4 w = *(const float4*)(wv + k);
        float4 bb = *(const float4*)(bv + k);
        acc += bb.x * s.x + bb.y * s.y + bb.z * s.z + bb.w * s.w;
        U4 o;
        o.h[0] = __float22bfloat162_rn(float2{s.x * w.x, s.y * w.y});
        o.h[1] = __float22bfloat162_rn(float2{s.z * w.z, s.w * w.w});
        *(ushort4*)(dst + k) = o.u;
    }
#pragma unroll
    for (int off = 32; off; off >>= 1) acc += __shfl_xor(acc, off);
    if (lane == 0) bdst[gw] = bsrc[gw] + acc;
}

// Plain f32 -> bf16 cast, 8 elems/thread
__global__ __launch_bounds__(256) void conv_cast_kernel(
    const float* __restrict__ src, unsigned short* __restrict__ dst, int n8)
{
    int i = blockIdx.x * 256 + threadIdx.x;
    if (i >= n8) return;
    const float* p = src + (size_t)i * 8;
    float4 v0 = *(const float4*)p;
    float4 v1 = *(const float4*)(p + 4);
    B8 r;
    r.h[0] = __float22bfloat162_rn(float2{v0.x, v0.y});
    r.h[1] = __float22bfloat162_rn(float2{v0.z, v0.w});
    r.h[2] = __float22bfloat162_rn(float2{v1.x, v1.y});
    r.h[3] = __float22bfloat162_rn(float2{v1.z, v1.w});
    *(bf16x8*)(dst + (size_t)i * 8) = r.v;
}

// ---------------------------------------------------------------------------
// Embedding gather + rotary; also emits per-row LN stats (mean, rstd)
// ---------------------------------------------------------------------------
__global__ __launch_bounds__(256) void embed_rot_kernel(
    const int* __restrict__ ids, const float* __restrict__ emb,
    float* __restrict__ x, float2* __restrict__ stats)
{
    const int tok = blockIdx.x;
    const int s = tok & (S_SZ - 1);
    const int id = ids[tok];
    const float* e = emb + (size_t)id * D_SZ;
    float* xo = x + (size_t)tok * D_SZ;
    const int t = threadIdx.x;

    float sum = 0.f, ssum = 0.f;
    if (t < 192) {
        float x0 = e[2 * t], x1 = e[2 * t + 1];
        float freq = powf(10000.f, -((float)(2 * t)) / 384.f);
        float ang = (float)s * freq;
        float sn, cs;
        sincosf(ang, &sn, &cs);
        float r0 = x0 * cs - x1 * sn;
        float r1 = x0 * sn + x1 * cs;
        xo[2 * t]     = r0;
        xo[2 * t + 1] = r1;
        sum += r0 + r1; ssum += r0 * r0 + r1 * r1;
    }
    {
        float e1 = e[384 + t];
        xo[384 + t] = e1;
        sum += e1; ssum += e1 * e1;
    }
    if (t < 128) {
        float e2 = e[640 + t];
        xo[640 + t] = e2;
        sum += e2; ssum += e2 * e2;
    }

    __shared__ float r1s[256], r2s[256];
    r1s[t] = sum; r2s[t] = ssum;
    __syncthreads();
    for (int off = 128; off; off >>= 1) {
        if (t < off) { r1s[t] += r1s[t + off]; r2s[t] += r2s[t + off]; }
        __syncthreads();
    }
    if (t == 0) {
        float mean = r1s[0] * (1.f / 768.f);
        float var = r2s[0] * (1.f / 768.f) - mean * mean;
        stats[tok] = float2{mean, rsqrtf(var + 1e-5f)};
    }
}

// ---------------------------------------------------------------------------
// Split-K reduce + LN stats: x[row] += bias + pp[0][row] + pp[1][row];
// then stats[row] = (mean, rstd) of the new row. One block per row.
// ---------------------------------------------------------------------------
__global__ __launch_bounds__(256) void reduce_ln_kernel(
    const float* __restrict__ pp, const float* __restrict__ bias,
    float* __restrict__ x, float2* __restrict__ stats)
{
    const int row = blockIdx.x;
    const int t = threadIdx.x;
    const size_t base = (size_t)row * D_SZ;
    const size_t E = (size_t)NTOK * D_SZ;

    float sum = 0.f, ssum = 0.f;
#pragma unroll
    for (int j = 0; j < 3; ++j) {
        int c = t + 256 * j;
        float v = x[base + c] + bias[c] + pp[base + c] + pp[E + base + c];
        x[base + c] = v;
        sum += v; ssum += v * v;
    }
    __shared__ float r1s[256], r2s[256];
    r1s[t] = sum; r2s[t] = ssum;
    __syncthreads();
    for (int off = 128; off; off >>= 1) {
        if (t < off) { r1s[t] += r1s[t + off]; r2s[t] += r2s[t + off]; }
        __syncthreads();
    }
    if (t == 0) {
        float mean = r1s[0] * (1.f / 768.f);
        float var = r2s[0] * (1.f / 768.f) - mean * mean;
        stats[row] = float2{mean, rsqrtf(var + 1e-5f)};
    }
}

// ---------------------------------------------------------------------------
// MFMA bf16 GEMM, single-step prefetch, REG-STAGED all sides (R10-best).
// LDS layout: linear 16B slots. Slot c holds (row = c>>2,
// ksg = ((c&3) + (c>>3)) & 3) -- K-subchunk swizzled WITHIN each row so:
//  * staging global reads stay coalesced
//  * staging LDS writes land at consecutive slots (conflict-free)
//  * fragment reads conflict-free (dsw = ((kgrp-(rc>>1))&3)*8).
//  AM: 0 f32 A; 1 f32 A + LN with PRECOMPUTED stats (BM==64); 2 bf16 A
//  CM: 0 f32 C (+Res); 1 qkv split epilogue; 2 GELU -> bf16 C;
//      3 raw f32 partial (split-K)
//  WB16: W bf16.  XSWZ: XCD swizzle.  CEP: per-block CE partials.
//  SPLITK: K-chunks along blockIdx.z.
// ---------------------------------------------------------------------------
template<int BM, int BN, int AM, int CM, bool WB16, bool XSWZ, bool CEP, int SPLITK>
__global__ __launch_bounds__(256) void mfma_gemm(
    const void* __restrict__ Av, const void* __restrict__ Wv,
    const float* __restrict__ bias, const float* __restrict__ Res,
    float* __restrict__ C,
    unsigned short* __restrict__ qp, unsigned short* __restrict__ kp,
    unsigned short* __restrict__ vp, float2* __restrict__ pm,
    const float2* __restrict__ stats,
    int M, int N, int K)
{
    constexpr int MR = BM / 32;
    constexpr int NR = BN / 32;
    constexpr int ACH = BM * 4 / 256;
    constexpr int BCH = BN * 4 / 256;

    __shared__ __align__(16) unsigned short As[2][BM * 32];
    __shared__ __align__(16) unsigned short Bs[2][BN * 32];
    __shared__ float smean[AM == 1 ? BM : 1];
    __shared__ float srstd[AM == 1 ? BM : 1];

    const int tid = threadIdx.x;
    const int lane = tid & 63;
    const int wave = tid >> 6;
    const int wrow0 = (wave >> 1) * (BM / 2);
    const int wcol0 = (wave & 1) * (BN / 2);
    const int kgrp = lane >> 4;
    const int rc = lane & 15;
    const int dsw = ((kgrp - (rc >> 1)) & 3) * 8;

    int m0, n0;
    if constexpr (XSWZ) {
        int id = blockIdx.y * gridDim.x + blockIdx.x;
        int cpx = (gridDim.x * gridDim.y) >> 3;
        int swz = (id & 7) * cpx + (id >> 3);
        m0 = (swz % gridDim.x) * BM;
        n0 = (swz / gridDim.x) * BN;
    } else {
        m0 = blockIdx.x * BM;
        n0 = blockIdx.y * BN;
    }
    const int kdiv = K / SPLITK;
    const int kbase = (SPLITK > 1) ? blockIdx.z * kdiv : 0;

    if constexpr (AM == 1) {
        if (tid < BM) {
            float2 st = stats[m0 + tid];
            smean[tid] = st.x; srstd[tid] = st.y;
        }
        __syncthreads();
    }

    f32x4 acc[MR][NR];
#pragma unroll
    for (int i = 0; i < MR; ++i)
#pragma unroll
        for (int j = 0; j < NR; ++j) acc[i][j] = (f32x4){0.f, 0.f, 0.f, 0.f};

    float areg[(AM != 2) ? ACH : 1][8];
    bf16x8 areg16[(AM == 2) ? ACH : 1];
    float bregf[WB16 ? 1 : BCH][8];
    bf16x8 breg16[WB16 ? BCH : 1];

    auto load_a = [&](int k0) {
#pragma unroll
        for (int i = 0; i < ACH; ++i) {
            int c = tid + i * 256;
            int row = c >> 2, ksg = ((c & 3) + (c >> 3)) & 3;
            if constexpr (AM == 2) {
                const unsigned short* A16 = (const unsigned short*)Av;
                areg16[i] = *(const bf16x8*)(A16 + (size_t)(m0 + row) * K + k0 + ksg * 8);
            } else {
                const float* p = (const float*)Av + (size_t)(m0 + row) * K + k0 + ksg * 8;
                float4 v0 = *(const float4*)p;
                float4 v1 = *(const float4*)(p + 4);
                areg[i][0] = v0.x; areg[i][1] = v0.y; areg[i][2] = v0.z; areg[i][3] = v0.w;
                areg[i][4] = v1.x; areg[i][5] = v1.y; areg[i][6] = v1.z; areg[i][7] = v1.w;
            }
        }
    };
    auto write_a = [&](int buf) {
#pragma unroll
        for (int i = 0; i < ACH; ++i) {
            int c = tid + i * 256;
            if constexpr (AM == 2) {
                *(bf16x8*)&As[buf][c * 8] = areg16[i];
            } else {
                int row = c >> 2;
                float sc = 1.f, sh = 0.f;
                if constexpr (AM == 1) { sc = srstd[row]; sh = -smean[row] * sc; }
                B8 r;
                r.h[0] = __float22bfloat162_rn(float2{fmaf(areg[i][0], sc, sh), fmaf(areg[i][1], sc, sh)});
                r.h[1] = __float22bfloat162_rn(float2{fmaf(areg[i][2], sc, sh), fmaf(areg[i][3], sc, sh)});
                r.h[2] = __float22bfloat162_rn(float2{fmaf(areg[i][4], sc, sh), fmaf(areg[i][5], sc, sh)});
                r.h[3] = __float22bfloat162_rn(float2{fmaf(areg[i][6], sc, sh), fmaf(areg[i][7], sc, sh)});
                *(bf16x8*)&As[buf][c * 8] = r.v;
            }
        }
    };

    auto load_b = [&](int k0) {
#pragma unroll
        for (int i = 0; i < BCH; ++i) {
            int c = tid + i * 256;
            int row = c >> 2, ksg = ((c & 3) + (c >> 3)) & 3;
            if constexpr (WB16) {
                const unsigned short* W16 = (const unsigned short*)Wv;
                breg16[i] = *(const bf16x8*)(W16 + (size_t)(n0 + row) * K + k0 + ksg * 8);
            } else {
                const float* p = (const float*)Wv + (size_t)(n0 + row) * K + k0 + ksg * 8;
                float4 v0 = *(const float4*)p;
                float4 v1 = *(const float4*)(p + 4);
                bregf[i][0] = v0.x; bregf[i][1] = v0.y; bregf[i][2] = v0.z; bregf[i][3] = v0.w;
                bregf[i][4] = v1.x; bregf[i][5] = v1.y; bregf[i][6] = v1.z; bregf[i][7] = v1.w;
            }
        }
    };
    auto write_b = [&](int buf) {
#pragma unroll
        for (int i = 0; i < BCH; ++i) {
            int c = tid + i * 256;
            if constexpr (WB16) {
                *(bf16x8*)&Bs[buf][c * 8] = breg16[i];
            } else {
                B8 r;
                r.h[0] = __float22bfloat162_rn(float2{bregf[i][0], bregf[i][1]});
                r.h[1] = __float22bfloat162_rn(float2{bregf[i][2], bregf[i][3]});
                r.h[2] = __float22bfloat162_rn(float2{bregf[i][4], bregf[i][5]});
                r.h[3] = __float22bfloat162_rn(float2{bregf[i][6], bregf[i][7]});
                *(bf16x8*)&Bs[buf][c * 8] = r.v;
            }
        }
    };

    auto compute = [&](int buf) {
        bf16x8 af[MR], bf[NR];
#pragma unroll
        for (int mi = 0; mi < MR; ++mi)
            af[mi] = *(const bf16x8*)&As[buf][(wrow0 + mi * 16 + rc) * 32 + dsw];
#pragma unroll
        for (int ni = 0; ni < NR; ++ni)
            bf[ni] = *(const bf16x8*)&Bs[buf][(wcol0 + ni * 16 + rc) * 32 + dsw];
#pragma unroll
        for (int mi = 0; mi < MR; ++mi)
#pragma unroll
            for (int ni = 0; ni < NR; ++ni)
                acc[mi][ni] = __builtin_amdgcn_mfma_f32_16x16x32_bf16(
                    af[mi], bf[ni], acc[mi][ni], 0, 0, 0);
    };

    load_a(kbase);
    load_b(kbase);
    write_a(0);
    write_b(0);
    __syncthreads();

    const int nk = kdiv >> 5;
    int cur = 0;
    for (int s = 0; s < nk; ++s) {
        const bool more = (s + 1 < nk);
        const int k1 = kbase + ((s + 1) << 5);
        if (more) { load_a(k1); load_b(k1); }
        compute(cur);
        if (more) { write_a(cur ^ 1); write_b(cur ^ 1); }
        __syncthreads();
        cur ^= 1;
    }

    // ---- epilogue ----
#pragma unroll
    for (int mi = 0; mi < MR; ++mi) {
#pragma unroll
        for (int ni = 0; ni < NR; ++ni) {
            const int col = n0 + wcol0 + ni * 16 + rc;
            const int rbase = m0 + wrow0 + mi * 16 + kgrp * 4;
            if constexpr (CM == 1) {
                float bv = bias[col];
                const int region = col / 768;
                const int c768 = col - region * 768;
                const int hh = c768 >> 6, d = c768 & 63;
                const int bb = rbase >> 10, s0 = rbase & 1023;
                const int bh = bb * H_SZ + hh;
                if (region == 0) {
#pragma unroll
                    for (int i = 0; i < 4; ++i)
                        qp[((size_t)(bh << 10) + s0 + i) * 64 + d]
                            = f2bf((acc[mi][ni][i] + bv) * 0.125f);
                } else if (region == 1) {
#pragma unroll
                    for (int i = 0; i < 4; ++i)
                        kp[((size_t)(bh << 10) + s0 + i) * 64 + d]
                            = f2bf(acc[mi][ni][i] + bv);
                } else {
                    U4E t4;
#pragma unroll
                    for (int i = 0; i < 4; ++i) t4.e[i] = f2bf(acc[mi][ni][i] + bv);
                    *(ushort4*)&vp[(((size_t)bh * 64 + d) << 10) + s0] = t4.u;
                }
            } else if constexpr (CM == 2) {
                float bv = bias[col];
                unsigned short* C16 = (unsigned short*)C;
#pragma unroll
                for (int i = 0; i < 4; ++i) {
                    float v = acc[mi][ni][i] + bv;
                    v = 0.5f * v * (1.f + erff(v * 0.70710678118654752f));
                    C16[(size_t)(rbase + i) * N + col] = f2bf(v);
                }
            } else if constexpr (CM == 3) {
                float* P = C + (size_t)blockIdx.z * ((size_t)M * N);
                size_t basei = (size_t)rbase * N + col;
#pragma unroll
                for (int i = 0; i < 4; ++i)
                    P[basei + (size_t)i * N] = acc[mi][ni][i];
            } else {
                float bv = bias ? bias[col] : 0.f;
                size_t basei = (size_t)rbase * N + col;
#pragma unroll
                for (int i = 0; i < 4; ++i) {
                    float v = acc[mi][ni][i] + bv;
                    size_t idx = basei + (size_t)i * N;
                    if (Res) v += Res[idx];
                    C[idx] = v;
                }
            }
        }
    }

    // ---- fused CE partials ----
    if constexpr (CEP) {
        float2 (*sce)[2] = (float2 (*)[2])As;
        float bvv[NR];
#pragma unroll
        for (int ni = 0; ni < NR; ++ni) bvv[ni] = bias[n0 + wcol0 + ni * 16 + rc];
#pragma unroll
        for (int mi = 0; mi < MR; ++mi) {
#pragma unroll
            for (int i = 0; i < 4; ++i) {
                float vmax = -1e30f;
#pragma unroll
                for (int ni = 0; ni < NR; ++ni)
                    vmax = fmaxf(vmax, acc[mi][ni][i] + bvv[ni]);
                vmax = fmaxf(vmax, __shfl_xor(vmax, 1));
                vmax = fmaxf(vmax, __shfl_xor(vmax, 2));
                vmax = fmaxf(vmax, __shfl_xor(vmax, 4));
                vmax = fmaxf(vmax, __shfl_xor(vmax, 8));
                float ssum = 0.f;
#pragma unroll
                for (int ni = 0; ni < NR; ++ni)
                    ssum += __expf(acc[mi][ni][i] + bvv[ni] - vmax);
                ssum += __shfl_xor(ssum, 1);
                ssum += __shfl_xor(ssum, 2);
                ssum += __shfl_xor(ssum, 4);
                ssum += __shfl_xor(ssum, 8);
                if (rc == 0)
                    sce[wrow0 + mi * 16 + kgrp * 4 + i][wave & 1] = float2{vmax, ssum};
            }
        }
        __syncthreads();
        if (tid < BM) {
            float2 a = sce[tid][0], b2 = sce[tid][1];
            float Mv = fmaxf(a.x, b2.x);
            float Sv = a.y * __expf(a.x - Mv) + b2.y * __expf(b2.x - Mv);
            pm[(size_t)(n0 >> 7) * NTOK + m0 + tid] = float2{Mv, Sv};
        }
    }
}

// ---------------------------------------------------------------------------
// attn3: kv-split-4 MFMA attention (unchanged)
// ---------------------------------------------------------------------------
__global__ __launch_bounds__(256) void attn3_kernel(
    const unsigned short* __restrict__ Q16, const unsigned short* __restrict__ K16,
    const unsigned short* __restrict__ VT16, unsigned short* __restrict__ ao16)
{
    const int bid = blockIdx.x;
    const int qb = 63 - bid / 24;          // heavy first
    const int bh = bid % 24;
    const int b = bh / H_SZ, h = bh % H_SZ;
    const int tid = threadIdx.x;
    const int w = tid >> 6, lane = tid & 63;
    const int g = lane >> 4, r = lane & 15;

    constexpr int KS = 72;
    __shared__ __align__(16) unsigned short Pl[4][16 * KS];
    __shared__ float so[4][16][66];
    __shared__ float2 sml[4][16];

    const unsigned short* Qb = Q16 + ((size_t)bh << 10) * 64;
    const unsigned short* Kb = K16 + ((size_t)bh << 10) * 64;
    const unsigned short* Vb = VT16 + ((size_t)bh << 6) * 1024;

    bf16x8 qf[2];
    qf[0] = *(const bf16x8*)&Qb[(qb * 16 + r) * 64 + 8 * g];
    qf[1] = *(const bf16x8*)&Qb[(qb * 16 + r) * 64 + 32 + 8 * g];

    float m_r = -1e30f, l_r = 0.f;
    f32x4 o[4];
#pragma unroll
    for (int ni = 0; ni < 4; ++ni) o[ni] = (f32x4){0.f, 0.f, 0.f, 0.f};

    const int nch = (qb >> 2) + 1;
    const int qbm = qb & 3;

    for (int c = w; c < nch; c += 4) {
        const bool lastc = (c == nch - 1);
        const int mi_hi = lastc ? qbm : 3;

        f32x4 s[4];
#pragma unroll
        for (int mi = 0; mi < 4; ++mi) s[mi] = (f32x4){0.f, 0.f, 0.f, 0.f};
#pragma unroll
        for (int mi = 0; mi < 4; ++mi) {
            if (mi <= mi_hi) {
#pragma unroll
                for (int ks = 0; ks < 2; ++ks) {
                    bf16x8 af = *(const bf16x8*)&Kb[(c * 64 + 16 * mi + r) * 64 + 32 * ks + 8 * g];
                    s[mi] = __builtin_amdgcn_mfma_f32_16x16x32_bf16(af, qf[ks], s[mi], 0, 0, 0);
                }
            }
        }

        float mx = -1e30f;
#pragma unroll
        for (int mi = 0; mi < 4; ++mi) {
            if (mi <= mi_hi) {
#pragma unroll
                for (int i = 0; i < 4; ++i) mx = fmaxf(mx, s[mi][i]);
            }
        }
        mx = fmaxf(mx, __shfl_xor(mx, 16));
        mx = fmaxf(mx, __shfl_xor(mx, 32));
        float m_new = fmaxf(m_r, mx);
        float corr = __expf(m_r - m_new);

        float p[4][4];
        float psum = 0.f;
#pragma unroll
        for (int mi = 0; mi < 4; ++mi) {
#pragma unroll
            for (int i = 0; i < 4; ++i) {
                float pv = (mi <= mi_hi) ? __expf(s[mi][i] - m_new) : 0.f;
                p[mi][i] = pv;
                psum += pv;
            }
        }
        psum += __shfl_xor(psum, 16);
        psum += __shfl_xor(psum, 32);
        l_r = l_r * corr + psum;
        m_r = m_new;

#pragma unroll
        for (int mi = 0; mi < 4; ++mi) {
            B4 t;
            t.h[0] = __float22bfloat162_rn(float2{p[mi][0], p[mi][1]});
            t.h[1] = __float22bfloat162_rn(float2{p[mi][2], p[mi][3]});
            *(bf16x4*)&Pl[w][r * KS + 16 * mi + 4 * g] = t.v;
        }

        float co[4];
#pragma unroll
        for (int i = 0; i < 4; ++i) co[i] = __shfl(corr, 4 * g + i);
#pragma unroll
        for (int ni = 0; ni < 4; ++ni)
#pragma unroll
            for (int i = 0; i < 4; ++i) o[ni][i] *= co[i];

#pragma unroll
        for (int ks = 0; ks < 2; ++ks) {
            if (!lastc || 2 * ks <= qbm) {
                bf16x8 pf = *(const bf16x8*)&Pl[w][r * KS + 32 * ks + 8 * g];
#pragma unroll
                for (int ni = 0; ni < 4; ++ni) {
                    bf16x8 vf = *(const bf16x8*)&Vb[(size_t)(r + 16 * ni) * 1024 + c * 64 + 32 * ks + 8 * g];
                    o[ni] = __builtin_amdgcn_mfma_f32_16x16x32_bf16(pf, vf, o[ni], 0, 0, 0);
                }
            }
        }
    }

    if (g == 0) sml[w][r] = float2{m_r, l_r};
#pragma unroll
    for (int ni = 0; ni < 4; ++ni)
#pragma unroll
        for (int i = 0; i < 4; ++i)
            so[w][4 * g + i][r + 16 * ni] = o[ni][i];
    __syncthreads();

#pragma unroll
    for (int j = 0; j < 4; ++j) {
        int e = tid + j * 256;
        int row = e >> 6, col = e & 63;
        float2 p0 = sml[0][row], p1 = sml[1][row], p2 = sml[2][row], p3 = sml[3][row];
        float M = fmaxf(fmaxf(p0.x, p1.x), fmaxf(p2.x, p3.x));
        float w0 = __expf(p0.x - M), w1 = __expf(p1.x - M);
        float w2 = __expf(p2.x - M), w3 = __expf(p3.x - M);
        float L = p0.y * w0 + p1.y * w1 + p2.y * w2 + p3.y * w3;
        float ov = so[0][row][col] * w0 + so[1][row][col] * w1
                 + so[2][row][col] * w2 + so[3][row][col] * w3;
        ao16[(size_t)(b * S_SZ + qb * 16 + row) * D_SZ + h * HD_SZ + col]
            = f2bf(ov / L);
    }
}

// ---------------------------------------------------------------------------
// CE: fallback full-row kernel (when ws too small for fused path)
// ---------------------------------------------------------------------------
__global__ __launch_bounds__(256) void ce2_kernel(
    const float* __restrict__ logits, const int* __restrict__ tgt,
    const int* __restrict__ inp, const float* __restrict__ noise,
    float* __restrict__ ce_row, float* __restrict__ msk_row)
{
    const int row = blockIdx.x;
    const int t = threadIdx.x;
    const float* lr = logits + (size_t)row * V_SZ;
    const float4* lr4 = (const float4*)lr;

    float m = -1e30f, s = 0.f;
    for (int i = t; i < V_SZ / 4; i += 256) {
        float4 v = lr4[i];
        float mx4 = fmaxf(fmaxf(v.x, v.y), fmaxf(v.z, v.w));
        if (mx4 > m) { s *= __expf(m - mx4); m = mx4; }
        s += __expf(v.x - m) + __expf(v.y - m) + __expf(v.z - m) + __expf(v.w - m);
    }

    __shared__ float sm[256], ss[256];
    sm[t] = m; ss[t] = s;
    __syncthreads();
    for (int off = 128; off; off >>= 1) {
        if (t < off) {
            float m2 = fmaxf(sm[t], sm[t + off]);
            ss[t] = ss[t] * __expf(sm[t] - m2) + ss[t + off] * __expf(sm[t + off] - m2);
            sm[t] = m2;
        }
        __syncthreads();
    }
    if (t == 0) {
        float M = sm[0], S = ss[0];
        int tg = tgt[row];
        float ce = -(lr[tg] - M - logf(S));
        int ism = (inp[row] == MASK_ID) ? 1 : 0;
        int b = row / S_SZ;
        ce_row[row] = ism ? (ce / noise[b]) : 0.f;
        msk_row[row] = ism ? 1.f : 0.f;
    }
}

// Reduce the 250 per-block partials per row (fused-CE path)
__global__ __launch_bounds__(64) void ce3_kernel(
    const float2* __restrict__ pm, const float* __restrict__ logits,
    const int* __restrict__ tgt, const int* __restrict__ inp,
    const float* __restrict__ noise, float* __restrict__ ce_row,
    float* __restrict__ msk_row)
{
    const int row = blockIdx.x * 64 + threadIdx.x;
    float m = -1e30f, s = 0.f;
    for (int bb = 0; bb < V_SZ / 128; ++bb) {
        float2 p = pm[(size_t)bb * NTOK + row];
        float M2 = fmaxf(m, p.x);
        s = s * __expf(m - M2) + p.y * __expf(p.x - M2);
        m = M2;
    }
    int tg = tgt[row];
    float lv = logits[(size_t)row * V_SZ + tg];
    float ce = -(lv - m - logf(s));
    int ism = (inp[row] == MASK_ID) ? 1 : 0;
    int b = row / S_SZ;
    ce_row[row] = ism ? (ce / noise[b]) : 0.f;
    msk_row[row] = ism ? 1.f : 0.f;
}

__global__ __launch_bounds__(256) void loss_reduce_kernel(
    const float* __restrict__ ce_row, const float* __restrict__ msk_row,
    float* __restrict__ out0)
{
    const int t = threadIdx.x;
    __shared__ float r1[256], r2[256];
    float s = 0.f, c = 0.f;
    for (int i = t; i < NTOK; i += 256) { s += ce_row[i]; c += msk_row[i]; }
    r1[t] = s; r2[t] = c;
    __syncthreads();
    for (int off = 128; off; off >>= 1) {
        if (t < off) { r1[t] += r1[t + off]; r2[t] += r2[t + off]; }
        __syncthreads();
    }
    if (t == 0) out0[0] = r1[0] / (r2[0] + 1e-8f);
}

// ---------------------------------------------------------------------------
// Host launch
// ---------------------------------------------------------------------------
extern "C" void kernel_launch(void* const* d_in, const int* in_sizes, int n_in,
                              void* d_out, int out_size, void* d_ws, size_t ws_size,
                              hipStream_t stream)
{
    const int*   input_ids  = (const int*)d_in[0];
    const int*   target_ids = (const int*)d_in[1];
    const float* noise      = (const float*)d_in[2];
    const float* emb        = (const float*)d_in[3];
    const float* in_w       = (const float*)d_in[4];
    const float* in_b       = (const float*)d_in[5];
    const float* aow        = (const float*)d_in[6];
    const float* aob        = (const float*)d_in[7];
    const float* ln1w       = (const float*)d_in[8];
    const float* ln1b       = (const float*)d_in[9];
    const float* ln2w       = (const float*)d_in[10];
    const float* ln2b       = (const float*)d_in[11];
    const float* w1         = (const float*)d_in[12];
    const float* b1         = (const float*)d_in[13];
    const float* w2         = (const float*)d_in[14];
    const float* b2         = (const float*)d_in[15];
    const float* projw      = (const float*)d_in[16];
    const float* projb      = (const float*)d_in[17];

    float* out    = (float*)d_out;
    float* logits = out + 1;

    // --- scratch inside d_out (dead before the logits GEMM overwrites) ---
    float* base = out + 4;
    unsigned short* wq16 = (unsigned short*)(base);               // 12x2304x768
    unsigned short* wa16 = (unsigned short*)(base + 10616832);    // 12x768x768
    unsigned short* w116 = (unsigned short*)(base + 14155776);    // 12x3072x768
    unsigned short* w216 = (unsigned short*)(base + 28311552);    // 12x768x3072
    float* qkvb2 = base + 42467328;                               // 12x2304
    float* b1b2  = qkvb2 + 27648;                                 // 12x3072
    unsigned short* Q16  = (unsigned short*)(base + 42531840);    // 24x1024x64
    unsigned short* K16  = (unsigned short*)(base + 43318272);
    unsigned short* VT16 = (unsigned short*)(base + 44104704);    // 24x64x1024
    unsigned short* ao16 = (unsigned short*)(base + 44891136);    // 2048x768
    unsigned short* mid16= (unsigned short*)(base + 45677568);    // 2048x3072
    float* pp            = base + 48823296;                       // 2x2048x768 f32
    // end: 4 + 51,969,024 < 65,536,001 ✓

    // --- d_ws: x f32 + CE rows + stats + optional xb16 + optional projw16 ---
    float* x       = (float*)d_ws;                 // [2048][768] f32
    float* ce_row  = x + (size_t)NTOK * D_SZ;
    float* msk_row = ce_row + NTOK;
    float2* stats  = (float2*)(msk_row + NTOK);    // [2048] (mean, rstd)
    unsigned short* xb16 = (unsigned short*)(msk_row + NTOK + 2 * NTOK);
    unsigned short* projw16 = xb16 + (size_t)NTOK * D_SZ;
    float2* pm = (float2*)d_ws;                    // CE partials reuse x (dead)
    const bool fA = ws_size >= 9469952ull;                  // room for xb16
    const bool fB = ws_size >= 58621952ull;                 // + projw16

    // --- one-time weight conversions ---
    conv_fold_kernel<<<6912, 256, 0, stream>>>(in_w, ln1w, ln1b, in_b, wq16, qkvb2, 2304);
    conv_fold_kernel<<<9216, 256, 0, stream>>>(w1, ln2w, ln2b, b1, w116, b1b2, 3072);
    conv_cast_kernel<<<3456, 256, 0, stream>>>(aow, wa16, 884736);
    conv_cast_kernel<<<13824, 256, 0, stream>>>(w2, w216, 3538944);
    if (fB)
        conv_cast_kernel<<<12000, 256, 0, stream>>>(projw, projw16, 3072000);

    embed_rot_kernel<<<NTOK, 256, 0, stream>>>(input_ids, emb, x, stats);

    for (int l = 0; l < L_SZ; ++l) {
        // qkv: LN1 from stats
        mfma_gemm<64, 128, 1, 1, true, false, false, 1><<<dim3(32, 18), 256, 0, stream>>>(
            x, wq16 + (size_t)l * 1769472, qkvb2 + l * 2304, nullptr, nullptr,
            Q16, K16, VT16, nullptr, stats, NTOK, 2304, 768);
        attn3_kernel<<<1536, 256, 0, stream>>>(Q16, K16, VT16, ao16);
        // attn-out: split-K=2 partials; reduce adds aob + residual, emits LN2 stats
        mfma_gemm<64, 64, 2, 3, true, false, false, 2><<<dim3(32, 12, 2), 256, 0, stream>>>(
            ao16, wa16 + (size_t)l * 589824, nullptr, nullptr, pp,
            nullptr, nullptr, nullptr, nullptr, nullptr, NTOK, 768, 768);
        reduce_ln_kernel<<<NTOK, 256, 0, stream>>>(pp, aob + l * D_SZ, x, stats);
        // ffn1: LN2 from stats, GELU -> bf16 mid
        mfma_gemm<64, 128, 1, 2, true, false, false, 1><<<dim3(32, 24), 256, 0, stream>>>(
            x, w116 + (size_t)l * 2359296, b1b2 + l * 3072, nullptr, (float*)mid16,
            nullptr, nullptr, nullptr, nullptr, stats, NTOK, 3072, 768);
        // ffn2: split-K=2 partials; reduce adds b2 + residual, emits LN1 stats
        mfma_gemm<64, 64, 2, 3, true, false, false, 2><<<dim3(32, 12, 2), 256, 0, stream>>>(
            mid16, w216 + (size_t)l * 2359296, nullptr, nullptr, pp,
            nullptr, nullptr, nullptr, nullptr, nullptr, NTOK, 768, 3072);
        reduce_ln_kernel<<<NTOK, 256, 0, stream>>>(pp, b2 + l * D_SZ, x, stats);
    }

    if (fA)
        conv_cast_kernel<<<768, 256, 0, stream>>>(x, xb16, 196608);

    if (fB) {
        mfma_gemm<128, 128, 2, 0, true, true, true, 1><<<dim3(16, 250), 256, 0, stream>>>(
            xb16, projw16, projb, nullptr, logits,
            nullptr, nullptr, nullptr, pm, nullptr, NTOK, V_SZ, 768);
        ce3_kernel<<<32, 64, 0, stream>>>(pm, logits, target_ids, input_ids,
                                          noise, ce_row, msk_row);
    } else if (fA) {
        mfma_gemm<128, 128, 2, 0, false, true, true, 1><<<dim3(16, 250), 256, 0, stream>>>(
            xb16, projw, projb, nullptr, logits,
            nullptr, nullptr, nullptr, pm, nullptr, NTOK, V_SZ, 768);
        ce3_kernel<<<32, 64, 0, stream>>>(pm, logits, target_ids, input_ids,
                                          noise, ce_row, msk_row);
    } else {
        mfma_gemm<128, 128, 0, 0, false, true, false, 1><<<dim3(16, 250), 256, 0, stream>>>(
            x, projw, projb, nullptr, logits,
            nullptr, nullptr, nullptr, nullptr, nullptr, NTOK, V_SZ, 768);
        ce2_kernel<<<NTOK, 256, 0, stream>>>(logits, target_ids, input_ids, noise,
                                             ce_row, msk_row);
    }

    loss_reduce_kernel<<<1, 256, 0, stream>>>(ce_row, msk_row, out);
}

// Round 15
// 2176.730 us; speedup vs baseline: 1.3080x; 1.0104x over previous
//
#include <hip/hip_runtime.h>
#include <hip/hip_bf16.h>
#include <math.h>

// Problem constants
#define V_SZ 32000
#define D_SZ 768
#define H_SZ 12
#define L_SZ 12
#define DF_SZ 3072
#define B_SZ 2
#define S_SZ 1024
#define BS_SZ 16
#define HD_SZ 64
#define MASK_ID 31999
#define NTOK (B_SZ * S_SZ)   // 2048

typedef __attribute__((ext_vector_type(8))) short bf16x8;
typedef __attribute__((ext_vector_type(4))) short bf16x4;
typedef __attribute__((ext_vector_type(4))) float f32x4;

union B8 { bf16x8 v; __hip_bfloat162 h[4]; };
union B4 { bf16x4 v; __hip_bfloat162 h[2]; };
union U4 { ushort4 u; __hip_bfloat162 h[2]; };
union U4E { ushort4 u; unsigned short e[4]; };

__device__ inline unsigned short f2bf(float x) {
    __hip_bfloat16 b = __float2bfloat16(x);
    union { __hip_bfloat16 b; unsigned short u; } c; c.b = b;
    return c.u;
}

// ---------------------------------------------------------------------------
// Weight conversion: fold ln scale into W rows, ln bias into GEMM bias.
// ---------------------------------------------------------------------------
__global__ __launch_bounds__(256) void conv_fold_kernel(
    const float* __restrict__ Wsrc, const float* __restrict__ lnw,
    const float* __restrict__ lnb, const float* __restrict__ bsrc,
    unsigned short* __restrict__ Wdst, float* __restrict__ bdst,
    int rows_per_layer)
{
    const int gw = (blockIdx.x * 256 + threadIdx.x) >> 6;
    const int lane = threadIdx.x & 63;
    const int l = gw / rows_per_layer;
    const float* src = Wsrc + (size_t)gw * D_SZ;
    const float* wv = lnw + l * D_SZ;
    const float* bv = lnb + l * D_SZ;
    unsigned short* dst = Wdst + (size_t)gw * D_SZ;
    float acc = 0.f;
#pragma unroll
    for (int j = 0; j < 3; ++j) {
        int k = lane * 4 + j * 256;
        float4 s = *(const float4*)(src + k);
        float4 w = *(const float4*)(wv + k);
        float4 bb = *(const float4*)(bv + k);
        acc += bb.x * s.x + bb.y * s.y + bb.z * s.z + bb.w * s.w;
        U4 o;
        o.h[0] = __float22bfloat162_rn(float2{s.x * w.x, s.y * w.y});
        o.h[1] = __float22bfloat162_rn(float2{s.z * w.z, s.w * w.w});
        *(ushort4*)(dst + k) = o.u;
    }
#pragma unroll
    for (int off = 32; off; off >>= 1) acc += __shfl_xor(acc, off);
    if (lane == 0) bdst[gw] = bsrc[gw] + acc;
}

// Plain f32 -> bf16 cast, 8 elems/thread
__global__ __launch_bounds__(256) void conv_cast_kernel(
    const float* __restrict__ src, unsigned short* __restrict__ dst, int n8)
{
    int i = blockIdx.x * 256 + threadIdx.x;
    if (i >= n8) return;
    const float* p = src + (size_t)i * 8;
    float4 v0 = *(const float4*)p;
    float4 v1 = *(const float4*)(p + 4);
    B8 r;
    r.h[0] = __float22bfloat162_rn(float2{v0.x, v0.y});
    r.h[1] = __float22bfloat162_rn(float2{v0.z, v0.w});
    r.h[2] = __float22bfloat162_rn(float2{v1.x, v1.y});
    r.h[3] = __float22bfloat162_rn(float2{v1.z, v1.w});
    *(bf16x8*)(dst + (size_t)i * 8) = r.v;
}

// ---------------------------------------------------------------------------
// Embedding gather + rotary; also emits per-row LN stats (mean, rstd)
// ---------------------------------------------------------------------------
__global__ __launch_bounds__(256) void embed_rot_kernel(
    const int* __restrict__ ids, const float* __restrict__ emb,
    float* __restrict__ x, float2* __restrict__ stats)
{
    const int tok = blockIdx.x;
    const int s = tok & (S_SZ - 1);
    const int id = ids[tok];
    const float* e = emb + (size_t)id * D_SZ;
    float* xo = x + (size_t)tok * D_SZ;
    const int t = threadIdx.x;

    float sum = 0.f, ssum = 0.f;
    if (t < 192) {
        float x0 = e[2 * t], x1 = e[2 * t + 1];
        float freq = powf(10000.f, -((float)(2 * t)) / 384.f);
        float ang = (float)s * freq;
        float sn, cs;
        sincosf(ang, &sn, &cs);
        float r0 = x0 * cs - x1 * sn;
        float r1 = x0 * sn + x1 * cs;
        xo[2 * t]     = r0;
        xo[2 * t + 1] = r1;
        sum += r0 + r1; ssum += r0 * r0 + r1 * r1;
    }
    {
        float e1 = e[384 + t];
        xo[384 + t] = e1;
        sum += e1; ssum += e1 * e1;
    }
    if (t < 128) {
        float e2 = e[640 + t];
        xo[640 + t] = e2;
        sum += e2; ssum += e2 * e2;
    }

    __shared__ float r1s[256], r2s[256];
    r1s[t] = sum; r2s[t] = ssum;
    __syncthreads();
    for (int off = 128; off; off >>= 1) {
        if (t < off) { r1s[t] += r1s[t + off]; r2s[t] += r2s[t + off]; }
        __syncthreads();
    }
    if (t == 0) {
        float mean = r1s[0] * (1.f / 768.f);
        float var = r2s[0] * (1.f / 768.f) - mean * mean;
        stats[tok] = float2{mean, rsqrtf(var + 1e-5f)};
    }
}

// ---------------------------------------------------------------------------
// Split-K reduce + LN stats: x[row] += bias + pp[0][row] + pp[1][row];
// then stats[row] = (mean, rstd) of the new row. One block per row.
// ---------------------------------------------------------------------------
__global__ __launch_bounds__(256) void reduce_ln_kernel(
    const float* __restrict__ pp, const float* __restrict__ bias,
    float* __restrict__ x, float2* __restrict__ stats)
{
    const int row = blockIdx.x;
    const int t = threadIdx.x;
    const size_t base = (size_t)row * D_SZ;
    const size_t E = (size_t)NTOK * D_SZ;

    float sum = 0.f, ssum = 0.f;
#pragma unroll
    for (int j = 0; j < 3; ++j) {
        int c = t + 256 * j;
        float v = x[base + c] + bias[c] + pp[base + c] + pp[E + base + c];
        x[base + c] = v;
        sum += v; ssum += v * v;
    }
    __shared__ float r1s[256], r2s[256];
    r1s[t] = sum; r2s[t] = ssum;
    __syncthreads();
    for (int off = 128; off; off >>= 1) {
        if (t < off) { r1s[t] += r1s[t + off]; r2s[t] += r2s[t + off]; }
        __syncthreads();
    }
    if (t == 0) {
        float mean = r1s[0] * (1.f / 768.f);
        float var = r2s[0] * (1.f / 768.f) - mean * mean;
        stats[row] = float2{mean, rsqrtf(var + 1e-5f)};
    }
}

// ---------------------------------------------------------------------------
// MFMA bf16 GEMM, single-step prefetch, REG-STAGED all sides.
// LDS layout: linear 16B slots. Slot c holds (row = c>>2,
// ksg = ((c&3) + (c>>3)) & 3) -- K-subchunk swizzled within each row:
// coalesced global reads, conflict-free LDS writes AND reads
// (dsw = ((kgrp-(rc>>1))&3)*8).
//  AM: 0 f32 A; 1 f32 A + LN with PRECOMPUTED stats; 2 bf16 A
//  CM: 0 f32 C (+Res); 1 qkv split epilogue; 2 GELU -> bf16 C;
//      3 raw f32 partial (split-K)
//  WB16: W bf16.  XSWZ: XCD swizzle.  CEP: per-block CE partials
//  (pm slot width = BN cols).  SPLITK: K-chunks along blockIdx.z.
//  NT: block threads.  WN: waves along N (WM = NT/64/WN = 2 always here).
// ---------------------------------------------------------------------------
template<int BM, int BN, int AM, int CM, bool WB16, bool XSWZ, bool CEP,
         int SPLITK, int NT = 256, int WN = 2>
__global__ __launch_bounds__(NT) void mfma_gemm(
    const void* __restrict__ Av, const void* __restrict__ Wv,
    const float* __restrict__ bias, const float* __restrict__ Res,
    float* __restrict__ C,
    unsigned short* __restrict__ qp, unsigned short* __restrict__ kp,
    unsigned short* __restrict__ vp, float2* __restrict__ pm,
    const float2* __restrict__ stats,
    int M, int N, int K)
{
    constexpr int WM = (NT / 64) / WN;          // 2 for all configs used
    constexpr int MR = (BM / WM) / 16;
    constexpr int NR = (BN / WN) / 16;
    constexpr int ACH = BM * 4 / NT;
    constexpr int BCH = BN * 4 / NT;

    __shared__ __align__(16) unsigned short As[2][BM * 32];
    __shared__ __align__(16) unsigned short Bs[2][BN * 32];
    __shared__ float smean[AM == 1 ? BM : 1];
    __shared__ float srstd[AM == 1 ? BM : 1];

    const int tid = threadIdx.x;
    const int lane = tid & 63;
    const int wave = tid >> 6;
    const int wrow0 = (wave / WN) * (BM / WM);
    const int wcol0 = (wave % WN) * (BN / WN);
    const int kgrp = lane >> 4;
    const int rc = lane & 15;
    const int dsw = ((kgrp - (rc >> 1)) & 3) * 8;

    int m0, n0;
    if constexpr (XSWZ) {
        int id = blockIdx.y * gridDim.x + blockIdx.x;
        int cpx = (gridDim.x * gridDim.y) >> 3;
        int swz = (id & 7) * cpx + (id >> 3);
        m0 = (swz % gridDim.x) * BM;
        n0 = (swz / gridDim.x) * BN;
    } else {
        m0 = blockIdx.x * BM;
        n0 = blockIdx.y * BN;
    }
    const int kdiv = K / SPLITK;
    const int kbase = (SPLITK > 1) ? blockIdx.z * kdiv : 0;

    if constexpr (AM == 1) {
        if (tid < BM) {
            float2 st = stats[m0 + tid];
            smean[tid] = st.x; srstd[tid] = st.y;
        }
        __syncthreads();
    }

    f32x4 acc[MR][NR];
#pragma unroll
    for (int i = 0; i < MR; ++i)
#pragma unroll
        for (int j = 0; j < NR; ++j) acc[i][j] = (f32x4){0.f, 0.f, 0.f, 0.f};

    float areg[(AM != 2) ? ACH : 1][8];
    bf16x8 areg16[(AM == 2) ? ACH : 1];
    float bregf[WB16 ? 1 : BCH][8];
    bf16x8 breg16[WB16 ? BCH : 1];

    auto load_a = [&](int k0) {
#pragma unroll
        for (int i = 0; i < ACH; ++i) {
            int c = tid + i * NT;
            int row = c >> 2, ksg = ((c & 3) + (c >> 3)) & 3;
            if constexpr (AM == 2) {
                const unsigned short* A16 = (const unsigned short*)Av;
                areg16[i] = *(const bf16x8*)(A16 + (size_t)(m0 + row) * K + k0 + ksg * 8);
            } else {
                const float* p = (const float*)Av + (size_t)(m0 + row) * K + k0 + ksg * 8;
                float4 v0 = *(const float4*)p;
                float4 v1 = *(const float4*)(p + 4);
                areg[i][0] = v0.x; areg[i][1] = v0.y; areg[i][2] = v0.z; areg[i][3] = v0.w;
                areg[i][4] = v1.x; areg[i][5] = v1.y; areg[i][6] = v1.z; areg[i][7] = v1.w;
            }
        }
    };
    auto write_a = [&](int buf) {
#pragma unroll
        for (int i = 0; i < ACH; ++i) {
            int c = tid + i * NT;
            if constexpr (AM == 2) {
                *(bf16x8*)&As[buf][c * 8] = areg16[i];
            } else {
                int row = c >> 2;
                float sc = 1.f, sh = 0.f;
                if constexpr (AM == 1) { sc = srstd[row]; sh = -smean[row] * sc; }
                B8 r;
                r.h[0] = __float22bfloat162_rn(float2{fmaf(areg[i][0], sc, sh), fmaf(areg[i][1], sc, sh)});
                r.h[1] = __float22bfloat162_rn(float2{fmaf(areg[i][2], sc, sh), fmaf(areg[i][3], sc, sh)});
                r.h[2] = __float22bfloat162_rn(float2{fmaf(areg[i][4], sc, sh), fmaf(areg[i][5], sc, sh)});
                r.h[3] = __float22bfloat162_rn(float2{fmaf(areg[i][6], sc, sh), fmaf(areg[i][7], sc, sh)});
                *(bf16x8*)&As[buf][c * 8] = r.v;
            }
        }
    };

    auto load_b = [&](int k0) {
#pragma unroll
        for (int i = 0; i < BCH; ++i) {
            int c = tid + i * NT;
            int row = c >> 2, ksg = ((c & 3) + (c >> 3)) & 3;
            if constexpr (WB16) {
                const unsigned short* W16 = (const unsigned short*)Wv;
                breg16[i] = *(const bf16x8*)(W16 + (size_t)(n0 + row) * K + k0 + ksg * 8);
            } else {
                const float* p = (const float*)Wv + (size_t)(n0 + row) * K + k0 + ksg * 8;
                float4 v0 = *(const float4*)p;
                float4 v1 = *(const float4*)(p + 4);
                bregf[i][0] = v0.x; bregf[i][1] = v0.y; bregf[i][2] = v0.z; bregf[i][3] = v0.w;
                bregf[i][4] = v1.x; bregf[i][5] = v1.y; bregf[i][6] = v1.z; bregf[i][7] = v1.w;
            }
        }
    };
    auto write_b = [&](int buf) {
#pragma unroll
        for (int i = 0; i < BCH; ++i) {
            int c = tid + i * NT;
            if constexpr (WB16) {
                *(bf16x8*)&Bs[buf][c * 8] = breg16[i];
            } else {
                B8 r;
                r.h[0] = __float22bfloat162_rn(float2{bregf[i][0], bregf[i][1]});
                r.h[1] = __float22bfloat162_rn(float2{bregf[i][2], bregf[i][3]});
                r.h[2] = __float22bfloat162_rn(float2{bregf[i][4], bregf[i][5]});
                r.h[3] = __float22bfloat162_rn(float2{bregf[i][6], bregf[i][7]});
                *(bf16x8*)&Bs[buf][c * 8] = r.v;
            }
        }
    };

    auto compute = [&](int buf) {
        bf16x8 af[MR], bf[NR];
#pragma unroll
        for (int mi = 0; mi < MR; ++mi)
            af[mi] = *(const bf16x8*)&As[buf][(wrow0 + mi * 16 + rc) * 32 + dsw];
#pragma unroll
        for (int ni = 0; ni < NR; ++ni)
            bf[ni] = *(const bf16x8*)&Bs[buf][(wcol0 + ni * 16 + rc) * 32 + dsw];
#pragma unroll
        for (int mi = 0; mi < MR; ++mi)
#pragma unroll
            for (int ni = 0; ni < NR; ++ni)
                acc[mi][ni] = __builtin_amdgcn_mfma_f32_16x16x32_bf16(
                    af[mi], bf[ni], acc[mi][ni], 0, 0, 0);
    };

    load_a(kbase);
    load_b(kbase);
    write_a(0);
    write_b(0);
    __syncthreads();

    const int nk = kdiv >> 5;
    int cur = 0;
    for (int s = 0; s < nk; ++s) {
        const bool more = (s + 1 < nk);
        const int k1 = kbase + ((s + 1) << 5);
        if (more) { load_a(k1); load_b(k1); }
        compute(cur);
        if (more) { write_a(cur ^ 1); write_b(cur ^ 1); }
        __syncthreads();
        cur ^= 1;
    }

    // ---- epilogue ----
#pragma unroll
    for (int mi = 0; mi < MR; ++mi) {
#pragma unroll
        for (int ni = 0; ni < NR; ++ni) {
            const int col = n0 + wcol0 + ni * 16 + rc;
            const int rbase = m0 + wrow0 + mi * 16 + kgrp * 4;
            if constexpr (CM == 1) {
                float bv = bias[col];
                const int region = col / 768;
                const int c768 = col - region * 768;
                const int hh = c768 >> 6, d = c768 & 63;
                const int bb = rbase >> 10, s0 = rbase & 1023;
                const int bh = bb * H_SZ + hh;
                if (region == 0) {
#pragma unroll
                    for (int i = 0; i < 4; ++i)
                        qp[((size_t)(bh << 10) + s0 + i) * 64 + d]
                            = f2bf((acc[mi][ni][i] + bv) * 0.125f);
                } else if (region == 1) {
#pragma unroll
                    for (int i = 0; i < 4; ++i)
                        kp[((size_t)(bh << 10) + s0 + i) * 64 + d]
                            = f2bf(acc[mi][ni][i] + bv);
                } else {
                    U4E t4;
#pragma unroll
                    for (int i = 0; i < 4; ++i) t4.e[i] = f2bf(acc[mi][ni][i] + bv);
                    *(ushort4*)&vp[(((size_t)bh * 64 + d) << 10) + s0] = t4.u;
                }
            } else if constexpr (CM == 2) {
                float bv = bias[col];
                unsigned short* C16 = (unsigned short*)C;
#pragma unroll
                for (int i = 0; i < 4; ++i) {
                    float v = acc[mi][ni][i] + bv;
                    v = 0.5f * v * (1.f + erff(v * 0.70710678118654752f));
                    C16[(size_t)(rbase + i) * N + col] = f2bf(v);
                }
            } else if constexpr (CM == 3) {
                float* P = C + (size_t)blockIdx.z * ((size_t)M * N);
                size_t basei = (size_t)rbase * N + col;
#pragma unroll
                for (int i = 0; i < 4; ++i)
                    P[basei + (size_t)i * N] = acc[mi][ni][i];
            } else {
                float bv = bias ? bias[col] : 0.f;
                size_t basei = (size_t)rbase * N + col;
#pragma unroll
                for (int i = 0; i < 4; ++i) {
                    float v = acc[mi][ni][i] + bv;
                    size_t idx = basei + (size_t)i * N;
                    if (Res) v += Res[idx];
                    C[idx] = v;
                }
            }
        }
    }

    // ---- fused CE partials (per-block row max & sumexp over BN cols) ----
    if constexpr (CEP) {
        float2 (*sce)[WN] = (float2 (*)[WN])As;   // reuse LDS (post-barrier)
        const int wn = wave % WN;
        float bvv[NR];
#pragma unroll
        for (int ni = 0; ni < NR; ++ni) bvv[ni] = bias[n0 + wcol0 + ni * 16 + rc];
#pragma unroll
        for (int mi = 0; mi < MR; ++mi) {
#pragma unroll
            for (int i = 0; i < 4; ++i) {
                float vmax = -1e30f;
#pragma unroll
                for (int ni = 0; ni < NR; ++ni)
                    vmax = fmaxf(vmax, acc[mi][ni][i] + bvv[ni]);
                vmax = fmaxf(vmax, __shfl_xor(vmax, 1));
                vmax = fmaxf(vmax, __shfl_xor(vmax, 2));
                vmax = fmaxf(vmax, __shfl_xor(vmax, 4));
                vmax = fmaxf(vmax, __shfl_xor(vmax, 8));
                float ssum = 0.f;
#pragma unroll
                for (int ni = 0; ni < NR; ++ni)
                    ssum += __expf(acc[mi][ni][i] + bvv[ni] - vmax);
                ssum += __shfl_xor(ssum, 1);
                ssum += __shfl_xor(ssum, 2);
                ssum += __shfl_xor(ssum, 4);
                ssum += __shfl_xor(ssum, 8);
                if (rc == 0)
                    sce[wrow0 + mi * 16 + kgrp * 4 + i][wn] = float2{vmax, ssum};
            }
        }
        __syncthreads();
        if (tid < BM) {
            float Mv = -1e30f;
#pragma unroll
            for (int j = 0; j < WN; ++j) Mv = fmaxf(Mv, sce[tid][j].x);
            float Sv = 0.f;
#pragma unroll
            for (int j = 0; j < WN; ++j)
                Sv += sce[tid][j].y * __expf(sce[tid][j].x - Mv);
            pm[(size_t)(n0 / BN) * NTOK + m0 + tid] = float2{Mv, Sv};
        }
    }
}

// ---------------------------------------------------------------------------
// attn3: kv-split-4 MFMA attention (unchanged)
// ---------------------------------------------------------------------------
__global__ __launch_bounds__(256) void attn3_kernel(
    const unsigned short* __restrict__ Q16, const unsigned short* __restrict__ K16,
    const unsigned short* __restrict__ VT16, unsigned short* __restrict__ ao16)
{
    const int bid = blockIdx.x;
    const int qb = 63 - bid / 24;          // heavy first
    const int bh = bid % 24;
    const int b = bh / H_SZ, h = bh % H_SZ;
    const int tid = threadIdx.x;
    const int w = tid >> 6, lane = tid & 63;
    const int g = lane >> 4, r = lane & 15;

    constexpr int KS = 72;
    __shared__ __align__(16) unsigned short Pl[4][16 * KS];
    __shared__ float so[4][16][66];
    __shared__ float2 sml[4][16];

    const unsigned short* Qb = Q16 + ((size_t)bh << 10) * 64;
    const unsigned short* Kb = K16 + ((size_t)bh << 10) * 64;
    const unsigned short* Vb = VT16 + ((size_t)bh << 6) * 1024;

    bf16x8 qf[2];
    qf[0] = *(const bf16x8*)&Qb[(qb * 16 + r) * 64 + 8 * g];
    qf[1] = *(const bf16x8*)&Qb[(qb * 16 + r) * 64 + 32 + 8 * g];

    float m_r = -1e30f, l_r = 0.f;
    f32x4 o[4];
#pragma unroll
    for (int ni = 0; ni < 4; ++ni) o[ni] = (f32x4){0.f, 0.f, 0.f, 0.f};

    const int nch = (qb >> 2) + 1;
    const int qbm = qb & 3;

    for (int c = w; c < nch; c += 4) {
        const bool lastc = (c == nch - 1);
        const int mi_hi = lastc ? qbm : 3;

        f32x4 s[4];
#pragma unroll
        for (int mi = 0; mi < 4; ++mi) s[mi] = (f32x4){0.f, 0.f, 0.f, 0.f};
#pragma unroll
        for (int mi = 0; mi < 4; ++mi) {
            if (mi <= mi_hi) {
#pragma unroll
                for (int ks = 0; ks < 2; ++ks) {
                    bf16x8 af = *(const bf16x8*)&Kb[(c * 64 + 16 * mi + r) * 64 + 32 * ks + 8 * g];
                    s[mi] = __builtin_amdgcn_mfma_f32_16x16x32_bf16(af, qf[ks], s[mi], 0, 0, 0);
                }
            }
        }

        float mx = -1e30f;
#pragma unroll
        for (int mi = 0; mi < 4; ++mi) {
            if (mi <= mi_hi) {
#pragma unroll
                for (int i = 0; i < 4; ++i) mx = fmaxf(mx, s[mi][i]);
            }
        }
        mx = fmaxf(mx, __shfl_xor(mx, 16));
        mx = fmaxf(mx, __shfl_xor(mx, 32));
        float m_new = fmaxf(m_r, mx);
        float corr = __expf(m_r - m_new);

        float p[4][4];
        float psum = 0.f;
#pragma unroll
        for (int mi = 0; mi < 4; ++mi) {
#pragma unroll
            for (int i = 0; i < 4; ++i) {
                float pv = (mi <= mi_hi) ? __expf(s[mi][i] - m_new) : 0.f;
                p[mi][i] = pv;
                psum += pv;
            }
        }
        psum += __shfl_xor(psum, 16);
        psum += __shfl_xor(psum, 32);
        l_r = l_r * corr + psum;
        m_r = m_new;

#pragma unroll
        for (int mi = 0; mi < 4; ++mi) {
            B4 t;
            t.h[0] = __float22bfloat162_rn(float2{p[mi][0], p[mi][1]});
            t.h[1] = __float22bfloat162_rn(float2{p[mi][2], p[mi][3]});
            *(bf16x4*)&Pl[w][r * KS + 16 * mi + 4 * g] = t.v;
        }

        float co[4];
#pragma unroll
        for (int i = 0; i < 4; ++i) co[i] = __shfl(corr, 4 * g + i);
#pragma unroll
        for (int ni = 0; ni < 4; ++ni)
#pragma unroll
            for (int i = 0; i < 4; ++i) o[ni][i] *= co[i];

#pragma unroll
        for (int ks = 0; ks < 2; ++ks) {
            if (!lastc || 2 * ks <= qbm) {
                bf16x8 pf = *(const bf16x8*)&Pl[w][r * KS + 32 * ks + 8 * g];
#pragma unroll
                for (int ni = 0; ni < 4; ++ni) {
                    bf16x8 vf = *(const bf16x8*)&Vb[(size_t)(r + 16 * ni) * 1024 + c * 64 + 32 * ks + 8 * g];
                    o[ni] = __builtin_amdgcn_mfma_f32_16x16x32_bf16(pf, vf, o[ni], 0, 0, 0);
                }
            }
        }
    }

    if (g == 0) sml[w][r] = float2{m_r, l_r};
#pragma unroll
    for (int ni = 0; ni < 4; ++ni)
#pragma unroll
        for (int i = 0; i < 4; ++i)
            so[w][4 * g + i][r + 16 * ni] = o[ni][i];
    __syncthreads();

#pragma unroll
    for (int j = 0; j < 4; ++j) {
        int e = tid + j * 256;
        int row = e >> 6, col = e & 63;
        float2 p0 = sml[0][row], p1 = sml[1][row], p2 = sml[2][row], p3 = sml[3][row];
        float M = fmaxf(fmaxf(p0.x, p1.x), fmaxf(p2.x, p3.x));
        float w0 = __expf(p0.x - M), w1 = __expf(p1.x - M);
        float w2 = __expf(p2.x - M), w3 = __expf(p3.x - M);
        float L = p0.y * w0 + p1.y * w1 + p2.y * w2 + p3.y * w3;
        float ov = so[0][row][col] * w0 + so[1][row][col] * w1
                 + so[2][row][col] * w2 + so[3][row][col] * w3;
        ao16[(size_t)(b * S_SZ + qb * 16 + row) * D_SZ + h * HD_SZ + col]
            = f2bf(ov / L);
    }
}

// ---------------------------------------------------------------------------
// CE: fallback full-row kernel (when ws too small for fused path)
// ---------------------------------------------------------------------------
__global__ __launch_bounds__(256) void ce2_kernel(
    const float* __restrict__ logits, const int* __restrict__ tgt,
    const int* __restrict__ inp, const float* __restrict__ noise,
    float* __restrict__ ce_row, float* __restrict__ msk_row)
{
    const int row = blockIdx.x;
    const int t = threadIdx.x;
    const float* lr = logits + (size_t)row * V_SZ;
    const float4* lr4 = (const float4*)lr;

    float m = -1e30f, s = 0.f;
    for (int i = t; i < V_SZ / 4; i += 256) {
        float4 v = lr4[i];
        float mx4 = fmaxf(fmaxf(v.x, v.y), fmaxf(v.z, v.w));
        if (mx4 > m) { s *= __expf(m - mx4); m = mx4; }
        s += __expf(v.x - m) + __expf(v.y - m) + __expf(v.z - m) + __expf(v.w - m);
    }

    __shared__ float sm[256], ss[256];
    sm[t] = m; ss[t] = s;
    __syncthreads();
    for (int off = 128; off; off >>= 1) {
        if (t < off) {
            float m2 = fmaxf(sm[t], sm[t + off]);
            ss[t] = ss[t] * __expf(sm[t] - m2) + ss[t + off] * __expf(sm[t + off] - m2);
            sm[t] = m2;
        }
        __syncthreads();
    }
    if (t == 0) {
        float M = sm[0], S = ss[0];
        int tg = tgt[row];
        float ce = -(lr[tg] - M - logf(S));
        int ism = (inp[row] == MASK_ID) ? 1 : 0;
        int b = row / S_SZ;
        ce_row[row] = ism ? (ce / noise[b]) : 0.f;
        msk_row[row] = ism ? 1.f : 0.f;
    }
}

// Reduce the 125 per-block partials per row (fused-CE path, 256-col blocks)
__global__ __launch_bounds__(64) void ce3_kernel(
    const float2* __restrict__ pm, const float* __restrict__ logits,
    const int* __restrict__ tgt, const int* __restrict__ inp,
    const float* __restrict__ noise, float* __restrict__ ce_row,
    float* __restrict__ msk_row)
{
    const int row = blockIdx.x * 64 + threadIdx.x;
    float m = -1e30f, s = 0.f;
    for (int bb = 0; bb < V_SZ / 256; ++bb) {
        float2 p = pm[(size_t)bb * NTOK + row];
        float M2 = fmaxf(m, p.x);
        s = s * __expf(m - M2) + p.y * __expf(p.x - M2);
        m = M2;
    }
    int tg = tgt[row];
    float lv = logits[(size_t)row * V_SZ + tg];
    float ce = -(lv - m - logf(s));
    int ism = (inp[row] == MASK_ID) ? 1 : 0;
    int b = row / S_SZ;
    ce_row[row] = ism ? (ce / noise[b]) : 0.f;
    msk_row[row] = ism ? 1.f : 0.f;
}

__global__ __launch_bounds__(256) void loss_reduce_kernel(
    const float* __restrict__ ce_row, const float* __restrict__ msk_row,
    float* __restrict__ out0)
{
    const int t = threadIdx.x;
    __shared__ float r1[256], r2[256];
    float s = 0.f, c = 0.f;
    for (int i = t; i < NTOK; i += 256) { s += ce_row[i]; c += msk_row[i]; }
    r1[t] = s; r2[t] = c;
    __syncthreads();
    for (int off = 128; off; off >>= 1) {
        if (t < off) { r1[t] += r1[t + off]; r2[t] += r2[t + off]; }
        __syncthreads();
    }
    if (t == 0) out0[0] = r1[0] / (r2[0] + 1e-8f);
}

// ---------------------------------------------------------------------------
// Host launch
// ---------------------------------------------------------------------------
extern "C" void kernel_launch(void* const* d_in, const int* in_sizes, int n_in,
                              void* d_out, int out_size, void* d_ws, size_t ws_size,
                              hipStream_t stream)
{
    const int*   input_ids  = (const int*)d_in[0];
    const int*   target_ids = (const int*)d_in[1];
    const float* noise      = (const float*)d_in[2];
    const float* emb        = (const float*)d_in[3];
    const float* in_w       = (const float*)d_in[4];
    const float* in_b       = (const float*)d_in[5];
    const float* aow        = (const float*)d_in[6];
    const float* aob        = (const float*)d_in[7];
    const float* ln1w       = (const float*)d_in[8];
    const float* ln1b       = (const float*)d_in[9];
    const float* ln2w       = (const float*)d_in[10];
    const float* ln2b       = (const float*)d_in[11];
    const float* w1         = (const float*)d_in[12];
    const float* b1         = (const float*)d_in[13];
    const float* w2         = (const float*)d_in[14];
    const float* b2         = (const float*)d_in[15];
    const float* projw      = (const float*)d_in[16];
    const float* projb      = (const float*)d_in[17];

    float* out    = (float*)d_out;
    float* logits = out + 1;

    // --- scratch inside d_out (dead before the logits GEMM overwrites) ---
    float* base = out + 4;
    unsigned short* wq16 = (unsigned short*)(base);               // 12x2304x768
    unsigned short* wa16 = (unsigned short*)(base + 10616832);    // 12x768x768
    unsigned short* w116 = (unsigned short*)(base + 14155776);    // 12x3072x768
    unsigned short* w216 = (unsigned short*)(base + 28311552);    // 12x768x3072
    float* qkvb2 = base + 42467328;                               // 12x2304
    float* b1b2  = qkvb2 + 27648;                                 // 12x3072
    unsigned short* Q16  = (unsigned short*)(base + 42531840);    // 24x1024x64
    unsigned short* K16  = (unsigned short*)(base + 43318272);
    unsigned short* VT16 = (unsigned short*)(base + 44104704);    // 24x64x1024
    unsigned short* ao16 = (unsigned short*)(base + 44891136);    // 2048x768
    unsigned short* mid16= (unsigned short*)(base + 45677568);    // 2048x3072
    float* pp            = base + 48823296;                       // 2x2048x768 f32
    // end: 4 + 51,969,024 < 65,536,001 ✓

    // --- d_ws: x f32 + CE rows + stats + optional xb16 + optional projw16 ---
    float* x       = (float*)d_ws;                 // [2048][768] f32
    float* ce_row  = x + (size_t)NTOK * D_SZ;
    float* msk_row = ce_row + NTOK;
    float2* stats  = (float2*)(msk_row + NTOK);    // [2048] (mean, rstd)
    unsigned short* xb16 = (unsigned short*)(msk_row + NTOK + 2 * NTOK);
    unsigned short* projw16 = xb16 + (size_t)NTOK * D_SZ;
    float2* pm = (float2*)d_ws;                    // CE partials reuse x (dead)
    const bool fA = ws_size >= 9469952ull;                  // room for xb16
    const bool fB = ws_size >= 58621952ull;                 // + projw16

    // --- one-time weight conversions ---
    conv_fold_kernel<<<6912, 256, 0, stream>>>(in_w, ln1w, ln1b, in_b, wq16, qkvb2, 2304);
    conv_fold_kernel<<<9216, 256, 0, stream>>>(w1, ln2w, ln2b, b1, w116, b1b2, 3072);
    conv_cast_kernel<<<3456, 256, 0, stream>>>(aow, wa16, 884736);
    conv_cast_kernel<<<13824, 256, 0, stream>>>(w2, w216, 3538944);
    if (fB)
        conv_cast_kernel<<<12000, 256, 0, stream>>>(projw, projw16, 3072000);

    embed_rot_kernel<<<NTOK, 256, 0, stream>>>(input_ids, emb, x, stats);

    for (int l = 0; l < L_SZ; ++l) {
        // qkv: LN1 from stats
        mfma_gemm<64, 128, 1, 1, true, false, false, 1><<<dim3(32, 18), 256, 0, stream>>>(
            x, wq16 + (size_t)l * 1769472, qkvb2 + l * 2304, nullptr, nullptr,
            Q16, K16, VT16, nullptr, stats, NTOK, 2304, 768);
        attn3_kernel<<<1536, 256, 0, stream>>>(Q16, K16, VT16, ao16);
        // attn-out: split-K=2 partials; reduce adds aob + residual, emits LN2 stats
        mfma_gemm<64, 64, 2, 3, true, false, false, 2><<<dim3(32, 12, 2), 256, 0, stream>>>(
            ao16, wa16 + (size_t)l * 589824, nullptr, nullptr, pp,
            nullptr, nullptr, nullptr, nullptr, nullptr, NTOK, 768, 768);
        reduce_ln_kernel<<<NTOK, 256, 0, stream>>>(pp, aob + l * D_SZ, x, stats);
        // ffn1: LN2 from stats, GELU -> bf16 mid
        mfma_gemm<64, 128, 1, 2, true, false, false, 1><<<dim3(32, 24), 256, 0, stream>>>(
            x, w116 + (size_t)l * 2359296, b1b2 + l * 3072, nullptr, (float*)mid16,
            nullptr, nullptr, nullptr, nullptr, stats, NTOK, 3072, 768);
        // ffn2: split-K=2 partials; reduce adds b2 + residual, emits LN1 stats
        mfma_gemm<64, 64, 2, 3, true, false, false, 2><<<dim3(32, 12, 2), 256, 0, stream>>>(
            mid16, w216 + (size_t)l * 2359296, nullptr, nullptr, pp,
            nullptr, nullptr, nullptr, nullptr, nullptr, NTOK, 768, 3072);
        reduce_ln_kernel<<<NTOK, 256, 0, stream>>>(pp, b2 + l * D_SZ, x, stats);
    }

    if (fA)
        conv_cast_kernel<<<768, 256, 0, stream>>>(x, xb16, 196608);

    if (fB) {
        mfma_gemm<128, 256, 2, 0, true, true, true, 1, 512, 4><<<dim3(16, 125), 512, 0, stream>>>(
            xb16, projw16, projb, nullptr, logits,
            nullptr, nullptr, nullptr, pm, nullptr, NTOK, V_SZ, 768);
        ce3_kernel<<<32, 64, 0, stream>>>(pm, logits, target_ids, input_ids,
                                          noise, ce_row, msk_row);
    } else if (fA) {
        mfma_gemm<128, 256, 2, 0, false, true, true, 1, 512, 4><<<dim3(16, 125), 512, 0, stream>>>(
            xb16, projw, projb, nullptr, logits,
            nullptr, nullptr, nullptr, pm, nullptr, NTOK, V_SZ, 768);
        ce3_kernel<<<32, 64, 0, stream>>>(pm, logits, target_ids, input_ids,
                                          noise, ce_row, msk_row);
    } else {
        mfma_gemm<128, 128, 0, 0, false, true, false, 1><<<dim3(16, 250), 256, 0, stream>>>(
            x, projw, projb, nullptr, logits,
            nullptr, nullptr, nullptr, nullptr, nullptr, NTOK, V_SZ, 768);
        ce2_kernel<<<NTOK, 256, 0, stream>>>(logits, target_ids, input_ids, noise,
                                             ce_row, msk_row);
    }

    loss_reduce_kernel<<<1, 256, 0, stream>>>(ce_row, msk_row, out);
}

// Round 16
// 2174.001 us; speedup vs baseline: 1.3096x; 1.0013x over previous
//
#include <hip/hip_runtime.h>
#include <hip/hip_bf16.h>
#include <math.h>

// Problem constants
#define V_SZ 32000
#define D_SZ 768
#define H_SZ 12
#define L_SZ 12
#define DF_SZ 3072
#define B_SZ 2
#define S_SZ 1024
#define BS_SZ 16
#define HD_SZ 64
#define MASK_ID 31999
#define NTOK (B_SZ * S_SZ)   // 2048

typedef __attribute__((ext_vector_type(8))) short bf16x8;
typedef __attribute__((ext_vector_type(4))) short bf16x4;
typedef __attribute__((ext_vector_type(4))) float f32x4;

union B8 { bf16x8 v; __hip_bfloat162 h[4]; };
union B4 { bf16x4 v; __hip_bfloat162 h[2]; };
union U4 { ushort4 u; __hip_bfloat162 h[2]; };
union U4E { ushort4 u; unsigned short e[4]; };

__device__ inline unsigned short f2bf(float x) {
    __hip_bfloat16 b = __float2bfloat16(x);
    union { __hip_bfloat16 b; unsigned short u; } c; c.b = b;
    return c.u;
}

// ---------------------------------------------------------------------------
// Weight conversion: fold ln scale into W rows, ln bias into GEMM bias.
// ---------------------------------------------------------------------------
__global__ __launch_bounds__(256) void conv_fold_kernel(
    const float* __restrict__ Wsrc, const float* __restrict__ lnw,
    const float* __restrict__ lnb, const float* __restrict__ bsrc,
    unsigned short* __restrict__ Wdst, float* __restrict__ bdst,
    int rows_per_layer)
{
    const int gw = (blockIdx.x * 256 + threadIdx.x) >> 6;
    const int lane = threadIdx.x & 63;
    const int l = gw / rows_per_layer;
    const float* src = Wsrc + (size_t)gw * D_SZ;
    const float* wv = lnw + l * D_SZ;
    const float* bv = lnb + l * D_SZ;
    unsigned short* dst = Wdst + (size_t)gw * D_SZ;
    float acc = 0.f;
#pragma unroll
    for (int j = 0; j < 3; ++j) {
        int k = lane * 4 + j * 256;
        float4 s = *(const float4*)(src + k);
        float4 w = *(const float4*)(wv + k);
        float4 bb = *(const float4*)(bv + k);
        acc += bb.x * s.x + bb.y * s.y + bb.z * s.z + bb.w * s.w;
        U4 o;
        o.h[0] = __float22bfloat162_rn(float2{s.x * w.x, s.y * w.y});
        o.h[1] = __float22bfloat162_rn(float2{s.z * w.z, s.w * w.w});
        *(ushort4*)(dst + k) = o.u;
    }
#pragma unroll
    for (int off = 32; off; off >>= 1) acc += __shfl_xor(acc, off);
    if (lane == 0) bdst[gw] = bsrc[gw] + acc;
}

// Plain f32 -> bf16 cast, 8 elems/thread
__global__ __launch_bounds__(256) void conv_cast_kernel(
    const float* __restrict__ src, unsigned short* __restrict__ dst, int n8)
{
    int i = blockIdx.x * 256 + threadIdx.x;
    if (i >= n8) return;
    const float* p = src + (size_t)i * 8;
    float4 v0 = *(const float4*)p;
    float4 v1 = *(const float4*)(p + 4);
    B8 r;
    r.h[0] = __float22bfloat162_rn(float2{v0.x, v0.y});
    r.h[1] = __float22bfloat162_rn(float2{v0.z, v0.w});
    r.h[2] = __float22bfloat162_rn(float2{v1.x, v1.y});
    r.h[3] = __float22bfloat162_rn(float2{v1.z, v1.w});
    *(bf16x8*)(dst + (size_t)i * 8) = r.v;
}

// ---------------------------------------------------------------------------
// Embedding gather + rotary; also emits per-row LN stats (mean, rstd)
// ---------------------------------------------------------------------------
__global__ __launch_bounds__(256) void embed_rot_kernel(
    const int* __restrict__ ids, const float* __restrict__ emb,
    float* __restrict__ x, float2* __restrict__ stats)
{
    const int tok = blockIdx.x;
    const int s = tok & (S_SZ - 1);
    const int id = ids[tok];
    const float* e = emb + (size_t)id * D_SZ;
    float* xo = x + (size_t)tok * D_SZ;
    const int t = threadIdx.x;

    float sum = 0.f, ssum = 0.f;
    if (t < 192) {
        float x0 = e[2 * t], x1 = e[2 * t + 1];
        float freq = powf(10000.f, -((float)(2 * t)) / 384.f);
        float ang = (float)s * freq;
        float sn, cs;
        sincosf(ang, &sn, &cs);
        float r0 = x0 * cs - x1 * sn;
        float r1 = x0 * sn + x1 * cs;
        xo[2 * t]     = r0;
        xo[2 * t + 1] = r1;
        sum += r0 + r1; ssum += r0 * r0 + r1 * r1;
    }
    {
        float e1 = e[384 + t];
        xo[384 + t] = e1;
        sum += e1; ssum += e1 * e1;
    }
    if (t < 128) {
        float e2 = e[640 + t];
        xo[640 + t] = e2;
        sum += e2; ssum += e2 * e2;
    }

    __shared__ float r1s[256], r2s[256];
    r1s[t] = sum; r2s[t] = ssum;
    __syncthreads();
    for (int off = 128; off; off >>= 1) {
        if (t < off) { r1s[t] += r1s[t + off]; r2s[t] += r2s[t + off]; }
        __syncthreads();
    }
    if (t == 0) {
        float mean = r1s[0] * (1.f / 768.f);
        float var = r2s[0] * (1.f / 768.f) - mean * mean;
        stats[tok] = float2{mean, rsqrtf(var + 1e-5f)};
    }
}

// ---------------------------------------------------------------------------
// Split-K reduce + LN stats: x[row] += bias + pp[0][row] + pp[1][row];
// then stats[row] = (mean, rstd) of the new row. Optionally also writes
// bf16 copy of the row (out16). One block per row.
// ---------------------------------------------------------------------------
__global__ __launch_bounds__(256) void reduce_ln_kernel(
    const float* __restrict__ pp, const float* __restrict__ bias,
    float* __restrict__ x, float2* __restrict__ stats,
    unsigned short* __restrict__ out16)
{
    const int row = blockIdx.x;
    const int t = threadIdx.x;
    const size_t base = (size_t)row * D_SZ;
    const size_t E = (size_t)NTOK * D_SZ;

    float sum = 0.f, ssum = 0.f;
#pragma unroll
    for (int j = 0; j < 3; ++j) {
        int c = t + 256 * j;
        float v = x[base + c] + bias[c] + pp[base + c] + pp[E + base + c];
        x[base + c] = v;
        if (out16) out16[base + c] = f2bf(v);
        sum += v; ssum += v * v;
    }
    __shared__ float r1s[256], r2s[256];
    r1s[t] = sum; r2s[t] = ssum;
    __syncthreads();
    for (int off = 128; off; off >>= 1) {
        if (t < off) { r1s[t] += r1s[t + off]; r2s[t] += r2s[t + off]; }
        __syncthreads();
    }
    if (t == 0) {
        float mean = r1s[0] * (1.f / 768.f);
        float var = r2s[0] * (1.f / 768.f) - mean * mean;
        stats[row] = float2{mean, rsqrtf(var + 1e-5f)};
    }
}

// ---------------------------------------------------------------------------
// MFMA bf16 GEMM, single-step prefetch, REG-STAGED all sides.
// LDS layout: linear 16B slots. Slot c holds (row = c>>2,
// ksg = ((c&3) + (c>>3)) & 3) -- K-subchunk swizzled within each row:
// coalesced global reads, conflict-free LDS writes AND reads
// (dsw = ((kgrp-(rc>>1))&3)*8).
//  AM: 0 f32 A; 1 f32 A + LN with PRECOMPUTED stats; 2 bf16 A
//  CM: 0 f32 C (+Res); 1 qkv split epilogue; 2 GELU -> bf16 C;
//      3 raw f32 partial (split-K)
//  WB16: W bf16.  XSWZ: XCD swizzle.  CEP: per-block CE partials
//  (pm slot width = BN cols).  SPLITK: K-chunks along blockIdx.z.
//  NT: block threads.  WN: waves along N.  WM = NT/64/WN.
// ---------------------------------------------------------------------------
template<int BM, int BN, int AM, int CM, bool WB16, bool XSWZ, bool CEP,
         int SPLITK, int NT = 256, int WN = 2>
__global__ __launch_bounds__(NT) void mfma_gemm(
    const void* __restrict__ Av, const void* __restrict__ Wv,
    const float* __restrict__ bias, const float* __restrict__ Res,
    float* __restrict__ C,
    unsigned short* __restrict__ qp, unsigned short* __restrict__ kp,
    unsigned short* __restrict__ vp, float2* __restrict__ pm,
    const float2* __restrict__ stats,
    int M, int N, int K)
{
    constexpr int WM = (NT / 64) / WN;
    constexpr int MR = (BM / WM) / 16;
    constexpr int NR = (BN / WN) / 16;
    constexpr int ACH = BM * 4 / NT;
    constexpr int BCH = BN * 4 / NT;

    __shared__ __align__(16) unsigned short As[2][BM * 32];
    __shared__ __align__(16) unsigned short Bs[2][BN * 32];
    __shared__ float smean[AM == 1 ? BM : 1];
    __shared__ float srstd[AM == 1 ? BM : 1];

    const int tid = threadIdx.x;
    const int lane = tid & 63;
    const int wave = tid >> 6;
    const int wrow0 = (wave / WN) * (BM / WM);
    const int wcol0 = (wave % WN) * (BN / WN);
    const int kgrp = lane >> 4;
    const int rc = lane & 15;
    const int dsw = ((kgrp - (rc >> 1)) & 3) * 8;

    int m0, n0;
    if constexpr (XSWZ) {
        int id = blockIdx.y * gridDim.x + blockIdx.x;
        int cpx = (gridDim.x * gridDim.y) >> 3;
        int swz = (id & 7) * cpx + (id >> 3);
        m0 = (swz % gridDim.x) * BM;
        n0 = (swz / gridDim.x) * BN;
    } else {
        m0 = blockIdx.x * BM;
        n0 = blockIdx.y * BN;
    }
    const int kdiv = K / SPLITK;
    const int kbase = (SPLITK > 1) ? blockIdx.z * kdiv : 0;

    if constexpr (AM == 1) {
        if (tid < BM) {
            float2 st = stats[m0 + tid];
            smean[tid] = st.x; srstd[tid] = st.y;
        }
        __syncthreads();
    }

    f32x4 acc[MR][NR];
#pragma unroll
    for (int i = 0; i < MR; ++i)
#pragma unroll
        for (int j = 0; j < NR; ++j) acc[i][j] = (f32x4){0.f, 0.f, 0.f, 0.f};

    float areg[(AM != 2) ? ACH : 1][8];
    bf16x8 areg16[(AM == 2) ? ACH : 1];
    float bregf[WB16 ? 1 : BCH][8];
    bf16x8 breg16[WB16 ? BCH : 1];

    auto load_a = [&](int k0) {
#pragma unroll
        for (int i = 0; i < ACH; ++i) {
            int c = tid + i * NT;
            int row = c >> 2, ksg = ((c & 3) + (c >> 3)) & 3;
            if constexpr (AM == 2) {
                const unsigned short* A16 = (const unsigned short*)Av;
                areg16[i] = *(const bf16x8*)(A16 + (size_t)(m0 + row) * K + k0 + ksg * 8);
            } else {
                const float* p = (const float*)Av + (size_t)(m0 + row) * K + k0 + ksg * 8;
                float4 v0 = *(const float4*)p;
                float4 v1 = *(const float4*)(p + 4);
                areg[i][0] = v0.x; areg[i][1] = v0.y; areg[i][2] = v0.z; areg[i][3] = v0.w;
                areg[i][4] = v1.x; areg[i][5] = v1.y; areg[i][6] = v1.z; areg[i][7] = v1.w;
            }
        }
    };
    auto write_a = [&](int buf) {
#pragma unroll
        for (int i = 0; i < ACH; ++i) {
            int c = tid + i * NT;
            if constexpr (AM == 2) {
                *(bf16x8*)&As[buf][c * 8] = areg16[i];
            } else {
                int row = c >> 2;
                float sc = 1.f, sh = 0.f;
                if constexpr (AM == 1) { sc = srstd[row]; sh = -smean[row] * sc; }
                B8 r;
                r.h[0] = __float22bfloat162_rn(float2{fmaf(areg[i][0], sc, sh), fmaf(areg[i][1], sc, sh)});
                r.h[1] = __float22bfloat162_rn(float2{fmaf(areg[i][2], sc, sh), fmaf(areg[i][3], sc, sh)});
                r.h[2] = __float22bfloat162_rn(float2{fmaf(areg[i][4], sc, sh), fmaf(areg[i][5], sc, sh)});
                r.h[3] = __float22bfloat162_rn(float2{fmaf(areg[i][6], sc, sh), fmaf(areg[i][7], sc, sh)});
                *(bf16x8*)&As[buf][c * 8] = r.v;
            }
        }
    };

    auto load_b = [&](int k0) {
#pragma unroll
        for (int i = 0; i < BCH; ++i) {
            int c = tid + i * NT;
            int row = c >> 2, ksg = ((c & 3) + (c >> 3)) & 3;
            if constexpr (WB16) {
                const unsigned short* W16 = (const unsigned short*)Wv;
                breg16[i] = *(const bf16x8*)(W16 + (size_t)(n0 + row) * K + k0 + ksg * 8);
            } else {
                const float* p = (const float*)Wv + (size_t)(n0 + row) * K + k0 + ksg * 8;
                float4 v0 = *(const float4*)p;
                float4 v1 = *(const float4*)(p + 4);
                bregf[i][0] = v0.x; bregf[i][1] = v0.y; bregf[i][2] = v0.z; bregf[i][3] = v0.w;
                bregf[i][4] = v1.x; bregf[i][5] = v1.y; bregf[i][6] = v1.z; bregf[i][7] = v1.w;
            }
        }
    };
    auto write_b = [&](int buf) {
#pragma unroll
        for (int i = 0; i < BCH; ++i) {
            int c = tid + i * NT;
            if constexpr (WB16) {
                *(bf16x8*)&Bs[buf][c * 8] = breg16[i];
            } else {
                B8 r;
                r.h[0] = __float22bfloat162_rn(float2{bregf[i][0], bregf[i][1]});
                r.h[1] = __float22bfloat162_rn(float2{bregf[i][2], bregf[i][3]});
                r.h[2] = __float22bfloat162_rn(float2{bregf[i][4], bregf[i][5]});
                r.h[3] = __float22bfloat162_rn(float2{bregf[i][6], bregf[i][7]});
                *(bf16x8*)&Bs[buf][c * 8] = r.v;
            }
        }
    };

    auto compute = [&](int buf) {
        bf16x8 af[MR], bf[NR];
#pragma unroll
        for (int mi = 0; mi < MR; ++mi)
            af[mi] = *(const bf16x8*)&As[buf][(wrow0 + mi * 16 + rc) * 32 + dsw];
#pragma unroll
        for (int ni = 0; ni < NR; ++ni)
            bf[ni] = *(const bf16x8*)&Bs[buf][(wcol0 + ni * 16 + rc) * 32 + dsw];
#pragma unroll
        for (int mi = 0; mi < MR; ++mi)
#pragma unroll
            for (int ni = 0; ni < NR; ++ni)
                acc[mi][ni] = __builtin_amdgcn_mfma_f32_16x16x32_bf16(
                    af[mi], bf[ni], acc[mi][ni], 0, 0, 0);
    };

    load_a(kbase);
    load_b(kbase);
    write_a(0);
    write_b(0);
    __syncthreads();

    const int nk = kdiv >> 5;
    int cur = 0;
    for (int s = 0; s < nk; ++s) {
        const bool more = (s + 1 < nk);
        const int k1 = kbase + ((s + 1) << 5);
        if (more) { load_a(k1); load_b(k1); }
        compute(cur);
        if (more) { write_a(cur ^ 1); write_b(cur ^ 1); }
        __syncthreads();
        cur ^= 1;
    }

    // ---- epilogue ----
#pragma unroll
    for (int mi = 0; mi < MR; ++mi) {
#pragma unroll
        for (int ni = 0; ni < NR; ++ni) {
            const int col = n0 + wcol0 + ni * 16 + rc;
            const int rbase = m0 + wrow0 + mi * 16 + kgrp * 4;
            if constexpr (CM == 1) {
                float bv = bias[col];
                const int region = col / 768;
                const int c768 = col - region * 768;
                const int hh = c768 >> 6, d = c768 & 63;
                const int bb = rbase >> 10, s0 = rbase & 1023;
                const int bh = bb * H_SZ + hh;
                if (region == 0) {
#pragma unroll
                    for (int i = 0; i < 4; ++i)
                        qp[((size_t)(bh << 10) + s0 + i) * 64 + d]
                            = f2bf((acc[mi][ni][i] + bv) * 0.125f);
                } else if (region == 1) {
#pragma unroll
                    for (int i = 0; i < 4; ++i)
                        kp[((size_t)(bh << 10) + s0 + i) * 64 + d]
                            = f2bf(acc[mi][ni][i] + bv);
                } else {
                    U4E t4;
#pragma unroll
                    for (int i = 0; i < 4; ++i) t4.e[i] = f2bf(acc[mi][ni][i] + bv);
                    *(ushort4*)&vp[(((size_t)bh * 64 + d) << 10) + s0] = t4.u;
                }
            } else if constexpr (CM == 2) {
                float bv = bias[col];
                unsigned short* C16 = (unsigned short*)C;
#pragma unroll
                for (int i = 0; i < 4; ++i) {
                    float v = acc[mi][ni][i] + bv;
                    v = 0.5f * v * (1.f + erff(v * 0.70710678118654752f));
                    C16[(size_t)(rbase + i) * N + col] = f2bf(v);
                }
            } else if constexpr (CM == 3) {
                float* P = C + (size_t)blockIdx.z * ((size_t)M * N);
                size_t basei = (size_t)rbase * N + col;
#pragma unroll
                for (int i = 0; i < 4; ++i)
                    P[basei + (size_t)i * N] = acc[mi][ni][i];
            } else {
                float bv = bias ? bias[col] : 0.f;
                size_t basei = (size_t)rbase * N + col;
#pragma unroll
                for (int i = 0; i < 4; ++i) {
                    float v = acc[mi][ni][i] + bv;
                    size_t idx = basei + (size_t)i * N;
                    if (Res) v += Res[idx];
                    C[idx] = v;
                }
            }
        }
    }

    // ---- fused CE partials (per-block row max & sumexp over BN cols) ----
    if constexpr (CEP) {
        float2 (*sce)[WN] = (float2 (*)[WN])As;   // reuse LDS (post-barrier)
        const int wn = wave % WN;
        float bvv[NR];
#pragma unroll
        for (int ni = 0; ni < NR; ++ni) bvv[ni] = bias[n0 + wcol0 + ni * 16 + rc];
#pragma unroll
        for (int mi = 0; mi < MR; ++mi) {
#pragma unroll
            for (int i = 0; i < 4; ++i) {
                float vmax = -1e30f;
#pragma unroll
                for (int ni = 0; ni < NR; ++ni)
                    vmax = fmaxf(vmax, acc[mi][ni][i] + bvv[ni]);
                vmax = fmaxf(vmax, __shfl_xor(vmax, 1));
                vmax = fmaxf(vmax, __shfl_xor(vmax, 2));
                vmax = fmaxf(vmax, __shfl_xor(vmax, 4));
                vmax = fmaxf(vmax, __shfl_xor(vmax, 8));
                float ssum = 0.f;
#pragma unroll
                for (int ni = 0; ni < NR; ++ni)
                    ssum += __expf(acc[mi][ni][i] + bvv[ni] - vmax);
                ssum += __shfl_xor(ssum, 1);
                ssum += __shfl_xor(ssum, 2);
                ssum += __shfl_xor(ssum, 4);
                ssum += __shfl_xor(ssum, 8);
                if (rc == 0)
                    sce[wrow0 + mi * 16 + kgrp * 4 + i][wn] = float2{vmax, ssum};
            }
        }
        __syncthreads();
        if (tid < BM) {
            float Mv = -1e30f;
#pragma unroll
            for (int j = 0; j < WN; ++j) Mv = fmaxf(Mv, sce[tid][j].x);
            float Sv = 0.f;
#pragma unroll
            for (int j = 0; j < WN; ++j)
                Sv += sce[tid][j].y * __expf(sce[tid][j].x - Mv);
            pm[(size_t)(n0 / BN) * NTOK + m0 + tid] = float2{Mv, Sv};
        }
    }
}

// ---------------------------------------------------------------------------
// attn3: kv-split-4 MFMA attention (unchanged)
// ---------------------------------------------------------------------------
__global__ __launch_bounds__(256) void attn3_kernel(
    const unsigned short* __restrict__ Q16, const unsigned short* __restrict__ K16,
    const unsigned short* __restrict__ VT16, unsigned short* __restrict__ ao16)
{
    const int bid = blockIdx.x;
    const int qb = 63 - bid / 24;          // heavy first
    const int bh = bid % 24;
    const int b = bh / H_SZ, h = bh % H_SZ;
    const int tid = threadIdx.x;
    const int w = tid >> 6, lane = tid & 63;
    const int g = lane >> 4, r = lane & 15;

    constexpr int KS = 72;
    __shared__ __align__(16) unsigned short Pl[4][16 * KS];
    __shared__ float so[4][16][66];
    __shared__ float2 sml[4][16];

    const unsigned short* Qb = Q16 + ((size_t)bh << 10) * 64;
    const unsigned short* Kb = K16 + ((size_t)bh << 10) * 64;
    const unsigned short* Vb = VT16 + ((size_t)bh << 6) * 1024;

    bf16x8 qf[2];
    qf[0] = *(const bf16x8*)&Qb[(qb * 16 + r) * 64 + 8 * g];
    qf[1] = *(const bf16x8*)&Qb[(qb * 16 + r) * 64 + 32 + 8 * g];

    float m_r = -1e30f, l_r = 0.f;
    f32x4 o[4];
#pragma unroll
    for (int ni = 0; ni < 4; ++ni) o[ni] = (f32x4){0.f, 0.f, 0.f, 0.f};

    const int nch = (qb >> 2) + 1;
    const int qbm = qb & 3;

    for (int c = w; c < nch; c += 4) {
        const bool lastc = (c == nch - 1);
        const int mi_hi = lastc ? qbm : 3;

        f32x4 s[4];
#pragma unroll
        for (int mi = 0; mi < 4; ++mi) s[mi] = (f32x4){0.f, 0.f, 0.f, 0.f};
#pragma unroll
        for (int mi = 0; mi < 4; ++mi) {
            if (mi <= mi_hi) {
#pragma unroll
                for (int ks = 0; ks < 2; ++ks) {
                    bf16x8 af = *(const bf16x8*)&Kb[(c * 64 + 16 * mi + r) * 64 + 32 * ks + 8 * g];
                    s[mi] = __builtin_amdgcn_mfma_f32_16x16x32_bf16(af, qf[ks], s[mi], 0, 0, 0);
                }
            }
        }

        float mx = -1e30f;
#pragma unroll
        for (int mi = 0; mi < 4; ++mi) {
            if (mi <= mi_hi) {
#pragma unroll
                for (int i = 0; i < 4; ++i) mx = fmaxf(mx, s[mi][i]);
            }
        }
        mx = fmaxf(mx, __shfl_xor(mx, 16));
        mx = fmaxf(mx, __shfl_xor(mx, 32));
        float m_new = fmaxf(m_r, mx);
        float corr = __expf(m_r - m_new);

        float p[4][4];
        float psum = 0.f;
#pragma unroll
        for (int mi = 0; mi < 4; ++mi) {
#pragma unroll
            for (int i = 0; i < 4; ++i) {
                float pv = (mi <= mi_hi) ? __expf(s[mi][i] - m_new) : 0.f;
                p[mi][i] = pv;
                psum += pv;
            }
        }
        psum += __shfl_xor(psum, 16);
        psum += __shfl_xor(psum, 32);
        l_r = l_r * corr + psum;
        m_r = m_new;

#pragma unroll
        for (int mi = 0; mi < 4; ++mi) {
            B4 t;
            t.h[0] = __float22bfloat162_rn(float2{p[mi][0], p[mi][1]});
            t.h[1] = __float22bfloat162_rn(float2{p[mi][2], p[mi][3]});
            *(bf16x4*)&Pl[w][r * KS + 16 * mi + 4 * g] = t.v;
        }

        float co[4];
#pragma unroll
        for (int i = 0; i < 4; ++i) co[i] = __shfl(corr, 4 * g + i);
#pragma unroll
        for (int ni = 0; ni < 4; ++ni)
#pragma unroll
            for (int i = 0; i < 4; ++i) o[ni][i] *= co[i];

#pragma unroll
        for (int ks = 0; ks < 2; ++ks) {
            if (!lastc || 2 * ks <= qbm) {
                bf16x8 pf = *(const bf16x8*)&Pl[w][r * KS + 32 * ks + 8 * g];
#pragma unroll
                for (int ni = 0; ni < 4; ++ni) {
                    bf16x8 vf = *(const bf16x8*)&Vb[(size_t)(r + 16 * ni) * 1024 + c * 64 + 32 * ks + 8 * g];
                    o[ni] = __builtin_amdgcn_mfma_f32_16x16x32_bf16(pf, vf, o[ni], 0, 0, 0);
                }
            }
        }
    }

    if (g == 0) sml[w][r] = float2{m_r, l_r};
#pragma unroll
    for (int ni = 0; ni < 4; ++ni)
#pragma unroll
        for (int i = 0; i < 4; ++i)
            so[w][4 * g + i][r + 16 * ni] = o[ni][i];
    __syncthreads();

#pragma unroll
    for (int j = 0; j < 4; ++j) {
        int e = tid + j * 256;
        int row = e >> 6, col = e & 63;
        float2 p0 = sml[0][row], p1 = sml[1][row], p2 = sml[2][row], p3 = sml[3][row];
        float M = fmaxf(fmaxf(p0.x, p1.x), fmaxf(p2.x, p3.x));
        float w0 = __expf(p0.x - M), w1 = __expf(p1.x - M);
        float w2 = __expf(p2.x - M), w3 = __expf(p3.x - M);
        float L = p0.y * w0 + p1.y * w1 + p2.y * w2 + p3.y * w3;
        float ov = so[0][row][col] * w0 + so[1][row][col] * w1
                 + so[2][row][col] * w2 + so[3][row][col] * w3;
        ao16[(size_t)(b * S_SZ + qb * 16 + row) * D_SZ + h * HD_SZ + col]
            = f2bf(ov / L);
    }
}

// ---------------------------------------------------------------------------
// CE: fallback full-row kernel (when ws too small for fused path)
// ---------------------------------------------------------------------------
__global__ __launch_bounds__(256) void ce2_kernel(
    const float* __restrict__ logits, const int* __restrict__ tgt,
    const int* __restrict__ inp, const float* __restrict__ noise,
    float* __restrict__ ce_row, float* __restrict__ msk_row)
{
    const int row = blockIdx.x;
    const int t = threadIdx.x;
    const float* lr = logits + (size_t)row * V_SZ;
    const float4* lr4 = (const float4*)lr;

    float m = -1e30f, s = 0.f;
    for (int i = t; i < V_SZ / 4; i += 256) {
        float4 v = lr4[i];
        float mx4 = fmaxf(fmaxf(v.x, v.y), fmaxf(v.z, v.w));
        if (mx4 > m) { s *= __expf(m - mx4); m = mx4; }
        s += __expf(v.x - m) + __expf(v.y - m) + __expf(v.z - m) + __expf(v.w - m);
    }

    __shared__ float sm[256], ss[256];
    sm[t] = m; ss[t] = s;
    __syncthreads();
    for (int off = 128; off; off >>= 1) {
        if (t < off) {
            float m2 = fmaxf(sm[t], sm[t + off]);
            ss[t] = ss[t] * __expf(sm[t] - m2) + ss[t + off] * __expf(sm[t + off] - m2);
            sm[t] = m2;
        }
        __syncthreads();
    }
    if (t == 0) {
        float M = sm[0], S = ss[0];
        int tg = tgt[row];
        float ce = -(lr[tg] - M - logf(S));
        int ism = (inp[row] == MASK_ID) ? 1 : 0;
        int b = row / S_SZ;
        ce_row[row] = ism ? (ce / noise[b]) : 0.f;
        msk_row[row] = ism ? 1.f : 0.f;
    }
}

// Reduce the 125 per-block partials per row (fused-CE path, 256-col blocks)
__global__ __launch_bounds__(64) void ce3_kernel(
    const float2* __restrict__ pm, const float* __restrict__ logits,
    const int* __restrict__ tgt, const int* __restrict__ inp,
    const float* __restrict__ noise, float* __restrict__ ce_row,
    float* __restrict__ msk_row)
{
    const int row = blockIdx.x * 64 + threadIdx.x;
    float m = -1e30f, s = 0.f;
    for (int bb = 0; bb < V_SZ / 256; ++bb) {
        float2 p = pm[(size_t)bb * NTOK + row];
        float M2 = fmaxf(m, p.x);
        s = s * __expf(m - M2) + p.y * __expf(p.x - M2);
        m = M2;
    }
    int tg = tgt[row];
    float lv = logits[(size_t)row * V_SZ + tg];
    float ce = -(lv - m - logf(s));
    int ism = (inp[row] == MASK_ID) ? 1 : 0;
    int b = row / S_SZ;
    ce_row[row] = ism ? (ce / noise[b]) : 0.f;
    msk_row[row] = ism ? 1.f : 0.f;
}

__global__ __launch_bounds__(256) void loss_reduce_kernel(
    const float* __restrict__ ce_row, const float* __restrict__ msk_row,
    float* __restrict__ out0)
{
    const int t = threadIdx.x;
    __shared__ float r1[256], r2[256];
    float s = 0.f, c = 0.f;
    for (int i = t; i < NTOK; i += 256) { s += ce_row[i]; c += msk_row[i]; }
    r1[t] = s; r2[t] = c;
    __syncthreads();
    for (int off = 128; off; off >>= 1) {
        if (t < off) { r1[t] += r1[t + off]; r2[t] += r2[t + off]; }
        __syncthreads();
    }
    if (t == 0) out0[0] = r1[0] / (r2[0] + 1e-8f);
}

// ---------------------------------------------------------------------------
// Host launch
// ---------------------------------------------------------------------------
extern "C" void kernel_launch(void* const* d_in, const int* in_sizes, int n_in,
                              void* d_out, int out_size, void* d_ws, size_t ws_size,
                              hipStream_t stream)
{
    const int*   input_ids  = (const int*)d_in[0];
    const int*   target_ids = (const int*)d_in[1];
    const float* noise      = (const float*)d_in[2];
    const float* emb        = (const float*)d_in[3];
    const float* in_w       = (const float*)d_in[4];
    const float* in_b       = (const float*)d_in[5];
    const float* aow        = (const float*)d_in[6];
    const float* aob        = (const float*)d_in[7];
    const float* ln1w       = (const float*)d_in[8];
    const float* ln1b       = (const float*)d_in[9];
    const float* ln2w       = (const float*)d_in[10];
    const float* ln2b       = (const float*)d_in[11];
    const float* w1         = (const float*)d_in[12];
    const float* b1         = (const float*)d_in[13];
    const float* w2         = (const float*)d_in[14];
    const float* b2         = (const float*)d_in[15];
    const float* projw      = (const float*)d_in[16];
    const float* projb      = (const float*)d_in[17];

    float* out    = (float*)d_out;
    float* logits = out + 1;

    // --- scratch inside d_out (dead before the logits GEMM overwrites) ---
    float* base = out + 4;
    unsigned short* wq16 = (unsigned short*)(base);               // 12x2304x768
    unsigned short* wa16 = (unsigned short*)(base + 10616832);    // 12x768x768
    unsigned short* w116 = (unsigned short*)(base + 14155776);    // 12x3072x768
    unsigned short* w216 = (unsigned short*)(base + 28311552);    // 12x768x3072
    float* qkvb2 = base + 42467328;                               // 12x2304
    float* b1b2  = qkvb2 + 27648;                                 // 12x3072
    unsigned short* Q16  = (unsigned short*)(base + 42531840);    // 24x1024x64
    unsigned short* K16  = (unsigned short*)(base + 43318272);
    unsigned short* VT16 = (unsigned short*)(base + 44104704);    // 24x64x1024
    unsigned short* ao16 = (unsigned short*)(base + 44891136);    // 2048x768
    unsigned short* mid16= (unsigned short*)(base + 45677568);    // 2048x3072
    float* pp            = base + 48823296;                       // 2x2048x768 f32
    // end: 4 + 51,969,024 < 65,536,001 ✓

    // --- d_ws: x f32 + CE rows + stats + optional xb16 + optional projw16 ---
    float* x       = (float*)d_ws;                 // [2048][768] f32
    float* ce_row  = x + (size_t)NTOK * D_SZ;
    float* msk_row = ce_row + NTOK;
    float2* stats  = (float2*)(msk_row + NTOK);    // [2048] (mean, rstd)
    unsigned short* xb16 = (unsigned short*)(msk_row + NTOK + 2 * NTOK);
    unsigned short* projw16 = xb16 + (size_t)NTOK * D_SZ;
    float2* pm = (float2*)d_ws;                    // CE partials reuse x (dead)
    const bool fA = ws_size >= 9469952ull;                  // room for xb16
    const bool fB = ws_size >= 58621952ull;                 // + projw16

    // --- one-time weight conversions ---
    conv_fold_kernel<<<6912, 256, 0, stream>>>(in_w, ln1w, ln1b, in_b, wq16, qkvb2, 2304);
    conv_fold_kernel<<<9216, 256, 0, stream>>>(w1, ln2w, ln2b, b1, w116, b1b2, 3072);
    conv_cast_kernel<<<3456, 256, 0, stream>>>(aow, wa16, 884736);
    conv_cast_kernel<<<13824, 256, 0, stream>>>(w2, w216, 3538944);
    if (fB)
        conv_cast_kernel<<<12000, 256, 0, stream>>>(projw, projw16, 3072000);

    embed_rot_kernel<<<NTOK, 256, 0, stream>>>(input_ids, emb, x, stats);

    for (int l = 0; l < L_SZ; ++l) {
        const bool last = (l == L_SZ - 1);
        // qkv: LN1 from stats
        mfma_gemm<64, 128, 1, 1, true, false, false, 1><<<dim3(32, 18), 256, 0, stream>>>(
            x, wq16 + (size_t)l * 1769472, qkvb2 + l * 2304, nullptr, nullptr,
            Q16, K16, VT16, nullptr, stats, NTOK, 2304, 768);
        attn3_kernel<<<1536, 256, 0, stream>>>(Q16, K16, VT16, ao16);
        // attn-out: split-K=2 partials; reduce adds aob + residual, emits LN2 stats
        mfma_gemm<64, 64, 2, 3, true, false, false, 2><<<dim3(32, 12, 2), 256, 0, stream>>>(
            ao16, wa16 + (size_t)l * 589824, nullptr, nullptr, pp,
            nullptr, nullptr, nullptr, nullptr, nullptr, NTOK, 768, 768);
        reduce_ln_kernel<<<NTOK, 256, 0, stream>>>(pp, aob + l * D_SZ, x, stats, nullptr);
        // ffn1: LN2 from stats, GELU -> bf16 mid
        mfma_gemm<64, 128, 1, 2, true, false, false, 1><<<dim3(32, 24), 256, 0, stream>>>(
            x, w116 + (size_t)l * 2359296, b1b2 + l * 3072, nullptr, (float*)mid16,
            nullptr, nullptr, nullptr, nullptr, stats, NTOK, 3072, 768);
        // ffn2: split-K=2 partials; reduce adds b2 + residual, emits stats
        // (and, on the last layer, the bf16 copy of x for the logits GEMM)
        mfma_gemm<64, 64, 2, 3, true, false, false, 2><<<dim3(32, 12, 2), 256, 0, stream>>>(
            mid16, w216 + (size_t)l * 2359296, nullptr, nullptr, pp,
            nullptr, nullptr, nullptr, nullptr, nullptr, NTOK, 768, 3072);
        reduce_ln_kernel<<<NTOK, 256, 0, stream>>>(pp, b2 + l * D_SZ, x, stats,
                                                   (last && fA) ? xb16 : nullptr);
    }

    if (fB) {
        mfma_gemm<256, 256, 2, 0, true, true, true, 1, 1024, 4><<<dim3(8, 125), 1024, 0, stream>>>(
            xb16, projw16, projb, nullptr, logits,
            nullptr, nullptr, nullptr, pm, nullptr, NTOK, V_SZ, 768);
        ce3_kernel<<<32, 64, 0, stream>>>(pm, logits, target_ids, input_ids,
                                          noise, ce_row, msk_row);
    } else if (fA) {
        mfma_gemm<256, 256, 2, 0, false, true, true, 1, 1024, 4><<<dim3(8, 125), 1024, 0, stream>>>(
            xb16, projw, projb, nullptr, logits,
            nullptr, nullptr, nullptr, pm, nullptr, NTOK, V_SZ, 768);
        ce3_kernel<<<32, 64, 0, stream>>>(pm, logits, target_ids, input_ids,
                                          noise, ce_row, msk_row);
    } else {
        mfma_gemm<128, 128, 0, 0, false, true, false, 1><<<dim3(16, 250), 256, 0, stream>>>(
            x, projw, projb, nullptr, logits,
            nullptr, nullptr, nullptr, nullptr, nullptr, NTOK, V_SZ, 768);
        ce2_kernel<<<NTOK, 256, 0, stream>>>(logits, target_ids, input_ids, noise,
                                             ce_row, msk_row);
    }

    loss_reduce_kernel<<<1, 256, 0, stream>>>(ce_row, msk_row, out);
}